// Round 3
// baseline (9726.708 us; speedup 1.0000x reference)
//
#include <hip/hip_runtime.h>
#include <hip/hip_bf16.h>
#include <math.h>

#define DIM 384
#define NH 12
#define HD 32
#define NWIN 2048          // B * 64 windows
#define TOKENS 100352      // B * 56 * 56
#define XKS 68             // xk stride (floats): 16B-aligned float4, reads are broadcast
#define WTS 65             // wt stride (floats): odd -> conflict-free strided reads
#define WLS 17             // proj/mlp weight stride (floats): odd -> conflict-free

typedef unsigned short u16;
typedef unsigned int u32;

__device__ __forceinline__ float b2f(u16 u){ return __uint_as_float(((u32)u) << 16); }
__device__ __forceinline__ u16 f2b(float f){
  u32 x = __float_as_uint(f);
  return (u16)((x + 0x7FFFu + ((x >> 16) & 1u)) >> 16);   // RNE
}

// ---------------- CPB bias table: tab[169][12] ----------------
__global__ void k_bias(const float* __restrict__ w1, const float* __restrict__ b1,
                       const float* __restrict__ w2, float* __restrict__ tab){
  __shared__ float hid[512];
  int e = blockIdx.x;
  int i = e / 13, j = e % 13;
  float t0 = (float)(i - 6) * (8.0f / 6.0f);
  float t1 = (float)(j - 6) * (8.0f / 6.0f);
  t0 = copysignf(log2f(fabsf(t0) + 1.f) * (1.f / 3.f), t0);
  t1 = copysignf(log2f(fabsf(t1) + 1.f) * (1.f / 3.f), t1);
  for (int jj = threadIdx.x; jj < 512; jj += blockDim.x)
    hid[jj] = fmaxf(w1[jj*2]*t0 + w1[jj*2+1]*t1 + b1[jj], 0.f);
  __syncthreads();
  if (threadIdx.x < 12){
    float s = 0.f;
    for (int jj = 0; jj < 512; ++jj) s += hid[jj] * w2[threadIdx.x*512 + jj];
    tab[e*12 + threadIdx.x] = s;
  }
}

// ---------------- fused QKV + cosine attention per (window, head) ----------------
__global__ __launch_bounds__(192) void k_attn(
    const float* __restrict__ x, const float* __restrict__ qkv_w,
    const float* __restrict__ q_bias, const float* __restrict__ v_bias,
    const float* __restrict__ logit_scale, const float* __restrict__ tab,
    u16* __restrict__ outwin){
  // phase1: xk [49][XKS] + wt [96][WTS]  (per 64-wide K chunk)
  // phase2 (aliased): qs/ks/vs [49*33]*3 + at [49*49]  = 7252 floats < 9572
  __shared__ __align__(16) float smem[49*XKS + 96*WTS];   // 9572 floats = 38288 B
  float* xk = smem;
  float* wt = smem + 49*XKS;
  float* qs = smem;
  float* ks = qs + 49*33;
  float* vs = ks + 49*33;
  float* at = vs + 49*33;

  int tid = threadIdx.x;
  int bid = blockIdx.x;
  int win = bid / 12, h = bid - win*12;
  int b = win >> 6, wi = win & 63;
  int wh = wi >> 3, ww = wi & 7;

  int c2 = tid % 48, rg = tid / 48;            // cols {c2, c2+48}, rows rg+4i
  int oc0 = c2, oc1 = c2 + 48;
  float acc0[13], acc1[13];
  for (int i = 0; i < 13; ++i){ acc0[i] = 0.f; acc1[i] = 0.f; }

  for (int kc = 0; kc < DIM; kc += 64){
    __syncthreads();
    // stage x chunk: 49 rows x 64 cols (float4 global, float4 LDS - aligned)
    for (int e = tid; e < 49*16; e += 192){
      int r = e >> 4, q = e & 15;
      int th = r / 7, tw = r - th*7;
      int gh = wh*7 + th + 3; if (gh >= 56) gh -= 56;
      int gw = ww*7 + tw + 3; if (gw >= 56) gw -= 56;
      float4 v = *(const float4*)(x + ((size_t)(b*3136 + gh*56 + gw))*DIM + kc + q*4);
      *(float4*)(xk + r*XKS + q*4) = v;
    }
    // stage weight chunk: 96 rows x 64 cols (float4 global, scalar LDS stores)
    for (int e = tid; e < 96*16; e += 192){
      int rr = e >> 4, q = e & 15;
      int m = rr >> 5, c = rr & 31;
      float4 v = *(const float4*)(qkv_w + (size_t)(m*DIM + h*HD + c)*DIM + kc + q*4);
      float* d = wt + rr*WTS + q*4;
      d[0] = v.x; d[1] = v.y; d[2] = v.z; d[3] = v.w;
    }
    __syncthreads();
    for (int kk = 0; kk < 64; kk += 4){
      float4 xv[13];
      #pragma unroll
      for (int i = 0; i < 13; ++i)             // rows >=49 read in-smem garbage, discarded later
        xv[i] = *(const float4*)(xk + (rg + 4*i)*XKS + kk);
      #pragma unroll
      for (int p = 0; p < 4; ++p){
        float w0  = wt[oc0*WTS + kk + p];
        float w1v = wt[oc1*WTS + kk + p];
        #pragma unroll
        for (int i = 0; i < 13; ++i){
          float xv_p = (&xv[i].x)[p];
          acc0[i] += xv_p*w0; acc1[i] += xv_p*w1v;
        }
      }
    }
  }
  __syncthreads();
  { // scatter to qs/ks/vs with qkv bias (k bias = 0)
    int m0 = oc0 >> 5, cc0 = oc0 & 31;
    int m1 = oc1 >> 5, cc1 = oc1 & 31;
    float bias0 = (m0==0) ? q_bias[h*HD+cc0] : (m0==2 ? v_bias[h*HD+cc0] : 0.f);
    float bias1 = (m1==0) ? q_bias[h*HD+cc1] : (m1==2 ? v_bias[h*HD+cc1] : 0.f);
    float* dst0 = (m0==0 ? qs : (m0==1 ? ks : vs)) + cc0;
    float* dst1 = (m1==0 ? qs : (m1==1 ? ks : vs)) + cc1;
    for (int i = 0; i < 13; ++i){
      int r = rg + 4*i;
      if (r < 49){ dst0[r*33] = acc0[i] + bias0; dst1[r*33] = acc1[i] + bias1; }
    }
  }
  __syncthreads();
  // cosine normalize rows; fold logit scale into q
  float sc = expf(fminf(logit_scale[h], 4.6051702f));
  if (tid < 98){
    int which = tid / 49, r = tid - which*49;
    float* S = which ? ks : qs;
    float ssq = 0.f;
    for (int c = 0; c < 32; ++c){ float v = S[r*33+c]; ssq += v*v; }
    float rinv = 1.f / fmaxf(sqrtf(ssq), 1e-12f);
    if (!which) rinv *= sc;
    for (int c = 0; c < 32; ++c) S[r*33+c] *= rinv;
  }
  __syncthreads();
  // scores + CPB bias + shift mask
  for (int e = tid; e < 49*49; e += 192){
    int i = e / 49, j = e - i*49;
    float d = 0.f;
    for (int c = 0; c < 32; ++c) d += qs[i*33+c]*ks[j*33+c];
    int ih = i/7, iw = i-ih*7, jh = j/7, jw = j-jh*7;
    float bv = tab[((ih-jh+6)*13 + (iw-jw+6))*12 + h];
    d += 16.f / (1.f + expf(-bv));
    int ghi = wh*7+ih, gwi = ww*7+iw, ghj = wh*7+jh, gwj = ww*7+jw;
    int zi = (ghi<49?0:(ghi<53?1:2))*3 + (gwi<49?0:(gwi<53?1:2));
    int zj = (ghj<49?0:(ghj<53?1:2))*3 + (gwj<49?0:(gwj<53?1:2));
    if (zi != zj) d -= 100.f;
    at[e] = d;
  }
  __syncthreads();
  if (tid < 49){ // row softmax
    float* row = at + tid*49;
    float m = row[0];
    for (int j = 1; j < 49; ++j) m = fmaxf(m, row[j]);
    float s = 0.f;
    for (int j = 0; j < 49; ++j){ float ev = expf(row[j]-m); row[j] = ev; s += ev; }
    float rs = 1.f/s;
    for (int j = 0; j < 49; ++j) row[j] *= rs;
  }
  __syncthreads();
  for (int e = tid; e < 49*32; e += 192){ // PV
    int r = e >> 5, c = e & 31;
    float o = 0.f;
    const float* ar = at + r*49;
    for (int j = 0; j < 49; ++j) o += ar[j]*vs[j*33+c];
    outwin[((size_t)win*49 + r)*DIM + h*HD + c] = f2b(o);
  }
}

// ---------------- proj + window-reverse + LN1 + residual -> x1 (in d_out) ----------------
__global__ __launch_bounds__(256) void k_proj(
    const u16* __restrict__ outwin, const float* __restrict__ proj_w,
    const float* __restrict__ proj_b, const float* __restrict__ x,
    const float* __restrict__ n1g, const float* __restrict__ n1b,
    float* __restrict__ x1){
  __shared__ __align__(16) float srcb[16*DIM];   // 24576 B
  __shared__ __align__(16) float wl[DIM*WLS];    // 26112 B
  int tid = threadIdx.x;
  int gt0 = blockIdx.x * 16;
  for (int e = tid; e < 16*96; e += 256){        // gather 16 token rows (bf16 -> f32)
    int tok = e / 96, q = e - tok*96;
    int gtok = gt0 + tok;
    int b = gtok / 3136, r2 = gtok - b*3136;
    int oh = r2 / 56, ow = r2 - oh*56;
    int hs = oh + 53; if (hs >= 56) hs -= 56;
    int ws2 = ow + 53; if (ws2 >= 56) ws2 -= 56;
    int win = b*64 + (hs/7)*8 + (ws2/7);
    int row = (hs%7)*7 + (ws2%7);
    ushort4 v = *(const ushort4*)(outwin + ((size_t)win*49 + row)*DIM + q*4);
    float* d = srcb + tok*DIM + q*4;
    d[0] = b2f(v.x); d[1] = b2f(v.y); d[2] = b2f(v.z); d[3] = b2f(v.w);
  }
  int tokr = tid >> 6, colc = tid & 63;          // wave w owns tokens {w, w+4, w+8, w+12}
  float acc[4][6];
  for (int j = 0; j < 6; ++j){
    float pb = proj_b[colc + 64*j];
    for (int i = 0; i < 4; ++i) acc[i][j] = pb;
  }
  for (int kc = 0; kc < DIM; kc += 16){
    __syncthreads();
    for (int e = tid; e < DIM*4; e += 256){
      int c = e >> 2, q = e & 3;
      float4 v = *(const float4*)(proj_w + (size_t)c*DIM + kc + q*4);
      float* d = wl + c*WLS + q*4;
      d[0] = v.x; d[1] = v.y; d[2] = v.z; d[3] = v.w;
    }
    __syncthreads();
    for (int kk = 0; kk < 16; ++kk){
      float sv[4];
      #pragma unroll
      for (int i = 0; i < 4; ++i) sv[i] = srcb[(tokr+4*i)*DIM + kc + kk];
      #pragma unroll
      for (int j = 0; j < 6; ++j){
        float wv = wl[(colc+64*j)*WLS + kk];
        #pragma unroll
        for (int i = 0; i < 4; ++i) acc[i][j] += sv[i]*wv;
      }
    }
  }
  for (int i = 0; i < 4; ++i){
    float s1 = 0.f, s2 = 0.f;
    for (int j = 0; j < 6; ++j){ s1 += acc[i][j]; s2 += acc[i][j]*acc[i][j]; }
    for (int off = 32; off; off >>= 1){ s1 += __shfl_xor(s1, off, 64); s2 += __shfl_xor(s2, off, 64); }
    float mu = s1*(1.f/384.f);
    float rstd = rsqrtf(s2*(1.f/384.f) - mu*mu + 1e-5f);
    size_t gbase = (size_t)(gt0 + tokr + 4*i)*DIM;
    for (int j = 0; j < 6; ++j){
      int c = colc + 64*j;
      x1[gbase + c] = (acc[i][j]-mu)*rstd*n1g[c] + n1b[c] + x[gbase + c];
    }
  }
}

// ---------------- fused MLP (384->1536 gelu ->384) + LN2 + residual ----------------
// x1 lives in d_out; in-place safe: block stages its 16 rows to LDS up front,
// writes only those rows at the end; blocks touch disjoint rows.
__global__ __launch_bounds__(256) void k_mlp(
    const float* __restrict__ x1, const float* __restrict__ w1, const float* __restrict__ b1,
    const float* __restrict__ w2, const float* __restrict__ b2,
    const float* __restrict__ n2g, const float* __restrict__ n2b,
    float* __restrict__ out){
  __shared__ __align__(16) float x1t[16*DIM];    // 24576 B
  __shared__ __align__(16) float hch[16*128];    // 8192 B
  __shared__ __align__(16) float wst[DIM*WLS];   // 26112 B
  int tid = threadIdx.x;
  int gt0 = blockIdx.x * 16;
  for (int e = tid; e < 16*96; e += 256)
    *(float4*)(x1t + e*4) = *(const float4*)(x1 + (size_t)gt0*DIM + e*4);
  int tokr = tid >> 6, colc = tid & 63;
  float acc2[4][6];
  for (int j = 0; j < 6; ++j){
    float bb = b2[colc + 64*j];
    for (int i = 0; i < 4; ++i) acc2[i][j] = bb;
  }
  for (int hc = 0; hc < 1536; hc += 128){
    float accH[4][2];
    for (int jj = 0; jj < 2; ++jj){
      float bb = b1[hc + colc + 64*jj];
      for (int i = 0; i < 4; ++i) accH[i][jj] = bb;
    }
    for (int kc = 0; kc < DIM; kc += 16){
      __syncthreads();                            // prev wst readers done
      for (int e = tid; e < 128*4; e += 256){
        int c = e >> 2, q = e & 3;
        float4 v = *(const float4*)(w1 + (size_t)(hc+c)*DIM + kc + q*4);
        float* d = wst + c*WLS + q*4;
        d[0] = v.x; d[1] = v.y; d[2] = v.z; d[3] = v.w;
      }
      __syncthreads();
      for (int kk = 0; kk < 16; ++kk){
        float xv[4];
        #pragma unroll
        for (int i = 0; i < 4; ++i) xv[i] = x1t[(tokr+4*i)*DIM + kc + kk];
        #pragma unroll
        for (int jj = 0; jj < 2; ++jj){
          float wv = wst[(colc+64*jj)*WLS + kk];
          #pragma unroll
          for (int i = 0; i < 4; ++i) accH[i][jj] += xv[i]*wv;
        }
      }
    }
    for (int i = 0; i < 4; ++i)                   // exact-erf GELU -> hidden chunk
      for (int jj = 0; jj < 2; ++jj){
        float v = accH[i][jj];
        hch[(tokr+4*i)*128 + colc + 64*jj] = 0.5f*v*(1.f + erff(v*0.70710678f));
      }
    for (int kk2 = 0; kk2 < 128; kk2 += 16){
      __syncthreads();                            // hch visible + prev wst readers done
      for (int e = tid; e < DIM*4; e += 256){
        int c = e >> 2, q = e & 3;
        float4 v = *(const float4*)(w2 + (size_t)c*1536 + hc + kk2 + q*4);
        float* d = wst + c*WLS + q*4;
        d[0] = v.x; d[1] = v.y; d[2] = v.z; d[3] = v.w;
      }
      __syncthreads();
      for (int kk = 0; kk < 16; ++kk){
        float hv[4];
        #pragma unroll
        for (int i = 0; i < 4; ++i) hv[i] = hch[(tokr+4*i)*128 + kk2 + kk];
        #pragma unroll
        for (int j = 0; j < 6; ++j){
          float wv = wst[(colc+64*j)*WLS + kk];
          #pragma unroll
          for (int i = 0; i < 4; ++i) acc2[i][j] += hv[i]*wv;
        }
      }
    }
  }
  for (int i = 0; i < 4; ++i){
    float s1 = 0.f, s2 = 0.f;
    for (int j = 0; j < 6; ++j){ s1 += acc2[i][j]; s2 += acc2[i][j]*acc2[i][j]; }
    for (int off = 32; off; off >>= 1){ s1 += __shfl_xor(s1, off, 64); s2 += __shfl_xor(s2, off, 64); }
    float mu = s1*(1.f/384.f);
    float rstd = rsqrtf(s2*(1.f/384.f) - mu*mu + 1e-5f);
    int tok = tokr + 4*i;
    size_t gbase = (size_t)(gt0+tok)*DIM;
    for (int j = 0; j < 6; ++j){
      int c = colc + 64*j;
      out[gbase + c] = x1t[tok*DIM + c] + (acc2[i][j]-mu)*rstd*n2g[c] + n2b[c];
    }
  }
}

extern "C" void kernel_launch(void* const* d_in, const int* in_sizes, int n_in,
                              void* d_out, int out_size, void* d_ws, size_t ws_size,
                              hipStream_t stream){
  const float* x           = (const float*)d_in[0];
  const float* qkv_w       = (const float*)d_in[1];
  const float* q_bias      = (const float*)d_in[2];
  const float* v_bias      = (const float*)d_in[3];
  const float* logit_scale = (const float*)d_in[4];
  const float* cpb_w1      = (const float*)d_in[5];
  const float* cpb_b1      = (const float*)d_in[6];
  const float* cpb_w2      = (const float*)d_in[7];
  const float* proj_w      = (const float*)d_in[8];
  const float* proj_b      = (const float*)d_in[9];
  const float* n1g         = (const float*)d_in[10];
  const float* n1b         = (const float*)d_in[11];
  const float* n2g         = (const float*)d_in[12];
  const float* n2b         = (const float*)d_in[13];
  const float* mlp_w1      = (const float*)d_in[14];
  const float* mlp_b1      = (const float*)d_in[15];
  const float* mlp_w2      = (const float*)d_in[16];
  const float* mlp_b2      = (const float*)d_in[17];

  // ws layout: tab (8 KB fp32) + outwin (77 MB bf16). x1 lives in d_out.
  char* ws = (char*)d_ws;
  float* tab   = (float*)ws;
  u16*  outwin = (u16*)(ws + 8192);
  float* x1    = (float*)d_out;
  float* out   = (float*)d_out;

  hipLaunchKernelGGL(k_bias, dim3(169), dim3(256), 0, stream, cpb_w1, cpb_b1, cpb_w2, tab);
  hipLaunchKernelGGL(k_attn, dim3(NWIN*NH), dim3(192), 0, stream,
                     x, qkv_w, q_bias, v_bias, logit_scale, tab, outwin);
  hipLaunchKernelGGL(k_proj, dim3(TOKENS/16), dim3(256), 0, stream,
                     outwin, proj_w, proj_b, x, n1g, n1b, x1);
  hipLaunchKernelGGL(k_mlp, dim3(TOKENS/16), dim3(256), 0, stream,
                     x1, mlp_w1, mlp_b1, mlp_w2, mlp_b2, n2g, n2b, out);
}

// Round 4
// 4664.817 us; speedup vs baseline: 2.0851x; 2.0851x over previous
//
#include <hip/hip_runtime.h>
#include <hip/hip_bf16.h>
#include <math.h>

#define DIM 384
#define NH 12
#define HD 32
#define NWIN 2048          // B * 64 windows
#define TOKENS 100352      // B * 56 * 56
#define XKS 68             // k_attn xk stride (floats)
#define WTS 65             // k_attn wt stride (floats)
#define WLS 17             // k_proj weight stride (floats)

typedef unsigned short u16;
typedef unsigned int u32;
typedef __attribute__((ext_vector_type(8))) short bf16x8;
typedef __attribute__((ext_vector_type(4))) float f32x4;

__device__ __forceinline__ float b2f(u16 u){ return __uint_as_float(((u32)u) << 16); }
__device__ __forceinline__ u16 f2b(float f){
  u32 x = __float_as_uint(f);
  return (u16)((x + 0x7FFFu + ((x >> 16) & 1u)) >> 16);   // RNE
}

// ---------------- weight pre-convert fp32 -> bf16 (tiny) ----------------
__global__ void k_wconv(const float* __restrict__ w1, const float* __restrict__ w2,
                        u16* __restrict__ w1bf, u16* __restrict__ w2bf){
  const int n = 1536*384;
  for (int i = blockIdx.x*blockDim.x + threadIdx.x; i < n; i += gridDim.x*blockDim.x){
    w1bf[i] = f2b(w1[i]);
    w2bf[i] = f2b(w2[i]);
  }
}

// ---------------- CPB bias table: tab[169][12] ----------------
__global__ void k_bias(const float* __restrict__ w1, const float* __restrict__ b1,
                       const float* __restrict__ w2, float* __restrict__ tab){
  __shared__ float hid[512];
  int e = blockIdx.x;
  int i = e / 13, j = e % 13;
  float t0 = (float)(i - 6) * (8.0f / 6.0f);
  float t1 = (float)(j - 6) * (8.0f / 6.0f);
  t0 = copysignf(log2f(fabsf(t0) + 1.f) * (1.f / 3.f), t0);
  t1 = copysignf(log2f(fabsf(t1) + 1.f) * (1.f / 3.f), t1);
  for (int jj = threadIdx.x; jj < 512; jj += blockDim.x)
    hid[jj] = fmaxf(w1[jj*2]*t0 + w1[jj*2+1]*t1 + b1[jj], 0.f);
  __syncthreads();
  if (threadIdx.x < 12){
    float s = 0.f;
    for (int jj = 0; jj < 512; ++jj) s += hid[jj] * w2[threadIdx.x*512 + jj];
    tab[e*12 + threadIdx.x] = s;
  }
}

// ---------------- fused QKV + cosine attention per (window, head) ----------------
__global__ __launch_bounds__(192) void k_attn(
    const float* __restrict__ x, const float* __restrict__ qkv_w,
    const float* __restrict__ q_bias, const float* __restrict__ v_bias,
    const float* __restrict__ logit_scale, const float* __restrict__ tab,
    u16* __restrict__ outwin){
  __shared__ __align__(16) float smem[49*XKS + 96*WTS];   // 9572 floats = 38288 B
  float* xk = smem;
  float* wt = smem + 49*XKS;
  float* qs = smem;
  float* ks = qs + 49*33;
  float* vs = ks + 49*33;
  float* at = vs + 49*33;

  int tid = threadIdx.x;
  int bid = blockIdx.x;
  int win = bid / 12, h = bid - win*12;
  int b = win >> 6, wi = win & 63;
  int wh = wi >> 3, ww = wi & 7;

  int c2 = tid % 48, rg = tid / 48;
  int oc0 = c2, oc1 = c2 + 48;
  float acc0[13], acc1[13];
  for (int i = 0; i < 13; ++i){ acc0[i] = 0.f; acc1[i] = 0.f; }

  for (int kc = 0; kc < DIM; kc += 64){
    __syncthreads();
    for (int e = tid; e < 49*16; e += 192){
      int r = e >> 4, q = e & 15;
      int th = r / 7, tw = r - th*7;
      int gh = wh*7 + th + 3; if (gh >= 56) gh -= 56;
      int gw = ww*7 + tw + 3; if (gw >= 56) gw -= 56;
      float4 v = *(const float4*)(x + ((size_t)(b*3136 + gh*56 + gw))*DIM + kc + q*4);
      *(float4*)(xk + r*XKS + q*4) = v;
    }
    for (int e = tid; e < 96*16; e += 192){
      int rr = e >> 4, q = e & 15;
      int m = rr >> 5, c = rr & 31;
      float4 v = *(const float4*)(qkv_w + (size_t)(m*DIM + h*HD + c)*DIM + kc + q*4);
      float* d = wt + rr*WTS + q*4;
      d[0] = v.x; d[1] = v.y; d[2] = v.z; d[3] = v.w;
    }
    __syncthreads();
    for (int kk = 0; kk < 64; kk += 4){
      float4 xv[13];
      #pragma unroll
      for (int i = 0; i < 13; ++i)
        xv[i] = *(const float4*)(xk + (rg + 4*i)*XKS + kk);
      #pragma unroll
      for (int p = 0; p < 4; ++p){
        float w0  = wt[oc0*WTS + kk + p];
        float w1v = wt[oc1*WTS + kk + p];
        #pragma unroll
        for (int i = 0; i < 13; ++i){
          float xv_p = (&xv[i].x)[p];
          acc0[i] += xv_p*w0; acc1[i] += xv_p*w1v;
        }
      }
    }
  }
  __syncthreads();
  {
    int m0 = oc0 >> 5, cc0 = oc0 & 31;
    int m1 = oc1 >> 5, cc1 = oc1 & 31;
    float bias0 = (m0==0) ? q_bias[h*HD+cc0] : (m0==2 ? v_bias[h*HD+cc0] : 0.f);
    float bias1 = (m1==0) ? q_bias[h*HD+cc1] : (m1==2 ? v_bias[h*HD+cc1] : 0.f);
    float* dst0 = (m0==0 ? qs : (m0==1 ? ks : vs)) + cc0;
    float* dst1 = (m1==0 ? qs : (m1==1 ? ks : vs)) + cc1;
    for (int i = 0; i < 13; ++i){
      int r = rg + 4*i;
      if (r < 49){ dst0[r*33] = acc0[i] + bias0; dst1[r*33] = acc1[i] + bias1; }
    }
  }
  __syncthreads();
  float sc = expf(fminf(logit_scale[h], 4.6051702f));
  if (tid < 98){
    int which = tid / 49, r = tid - which*49;
    float* S = which ? ks : qs;
    float ssq = 0.f;
    for (int c = 0; c < 32; ++c){ float v = S[r*33+c]; ssq += v*v; }
    float rinv = 1.f / fmaxf(sqrtf(ssq), 1e-12f);
    if (!which) rinv *= sc;
    for (int c = 0; c < 32; ++c) S[r*33+c] *= rinv;
  }
  __syncthreads();
  for (int e = tid; e < 49*49; e += 192){
    int i = e / 49, j = e - i*49;
    float d = 0.f;
    for (int c = 0; c < 32; ++c) d += qs[i*33+c]*ks[j*33+c];
    int ih = i/7, iw = i-ih*7, jh = j/7, jw = j-jh*7;
    float bv = tab[((ih-jh+6)*13 + (iw-jw+6))*12 + h];
    d += 16.f / (1.f + expf(-bv));
    int ghi = wh*7+ih, gwi = ww*7+iw, ghj = wh*7+jh, gwj = ww*7+jw;
    int zi = (ghi<49?0:(ghi<53?1:2))*3 + (gwi<49?0:(gwi<53?1:2));
    int zj = (ghj<49?0:(ghj<53?1:2))*3 + (gwj<49?0:(gwj<53?1:2));
    if (zi != zj) d -= 100.f;
    at[e] = d;
  }
  __syncthreads();
  if (tid < 49){
    float* row = at + tid*49;
    float m = row[0];
    for (int j = 1; j < 49; ++j) m = fmaxf(m, row[j]);
    float s = 0.f;
    for (int j = 0; j < 49; ++j){ float ev = expf(row[j]-m); row[j] = ev; s += ev; }
    float rs = 1.f/s;
    for (int j = 0; j < 49; ++j) row[j] *= rs;
  }
  __syncthreads();
  for (int e = tid; e < 49*32; e += 192){
    int r = e >> 5, c = e & 31;
    float o = 0.f;
    const float* ar = at + r*49;
    for (int j = 0; j < 49; ++j) o += ar[j]*vs[j*33+c];
    outwin[((size_t)win*49 + r)*DIM + h*HD + c] = f2b(o);
  }
}

// ---------------- proj + window-reverse + LN1 + residual -> x1 (in d_out) ----------------
__global__ __launch_bounds__(256) void k_proj(
    const u16* __restrict__ outwin, const float* __restrict__ proj_w,
    const float* __restrict__ proj_b, const float* __restrict__ x,
    const float* __restrict__ n1g, const float* __restrict__ n1b,
    float* __restrict__ x1){
  __shared__ __align__(16) float srcb[16*DIM];
  __shared__ __align__(16) float wl[DIM*WLS];
  int tid = threadIdx.x;
  int gt0 = blockIdx.x * 16;
  for (int e = tid; e < 16*96; e += 256){
    int tok = e / 96, q = e - tok*96;
    int gtok = gt0 + tok;
    int b = gtok / 3136, r2 = gtok - b*3136;
    int oh = r2 / 56, ow = r2 - oh*56;
    int hs = oh + 53; if (hs >= 56) hs -= 56;
    int ws2 = ow + 53; if (ws2 >= 56) ws2 -= 56;
    int win = b*64 + (hs/7)*8 + (ws2/7);
    int row = (hs%7)*7 + (ws2%7);
    ushort4 v = *(const ushort4*)(outwin + ((size_t)win*49 + row)*DIM + q*4);
    float* d = srcb + tok*DIM + q*4;
    d[0] = b2f(v.x); d[1] = b2f(v.y); d[2] = b2f(v.z); d[3] = b2f(v.w);
  }
  int tokr = tid >> 6, colc = tid & 63;
  float acc[4][6];
  for (int j = 0; j < 6; ++j){
    float pb = proj_b[colc + 64*j];
    for (int i = 0; i < 4; ++i) acc[i][j] = pb;
  }
  for (int kc = 0; kc < DIM; kc += 16){
    __syncthreads();
    for (int e = tid; e < DIM*4; e += 256){
      int c = e >> 2, q = e & 3;
      float4 v = *(const float4*)(proj_w + (size_t)c*DIM + kc + q*4);
      float* d = wl + c*WLS + q*4;
      d[0] = v.x; d[1] = v.y; d[2] = v.z; d[3] = v.w;
    }
    __syncthreads();
    for (int kk = 0; kk < 16; ++kk){
      float sv[4];
      #pragma unroll
      for (int i = 0; i < 4; ++i) sv[i] = srcb[(tokr+4*i)*DIM + kc + kk];
      #pragma unroll
      for (int j = 0; j < 6; ++j){
        float wv = wl[(colc+64*j)*WLS + kk];
        #pragma unroll
        for (int i = 0; i < 4; ++i) acc[i][j] += sv[i]*wv;
      }
    }
  }
  for (int i = 0; i < 4; ++i){
    float s1 = 0.f, s2 = 0.f;
    for (int j = 0; j < 6; ++j){ s1 += acc[i][j]; s2 += acc[i][j]*acc[i][j]; }
    for (int off = 32; off; off >>= 1){ s1 += __shfl_xor(s1, off, 64); s2 += __shfl_xor(s2, off, 64); }
    float mu = s1*(1.f/384.f);
    float rstd = rsqrtf(s2*(1.f/384.f) - mu*mu + 1e-5f);
    size_t gbase = (size_t)(gt0 + tokr + 4*i)*DIM;
    for (int j = 0; j < 6; ++j){
      int c = colc + 64*j;
      x1[gbase + c] = (acc[i][j]-mu)*rstd*n1g[c] + n1b[c] + x[gbase + c];
    }
  }
}

// ---------------- fused MLP via bf16 MFMA + LN2 + residual ----------------
// Block: 64 tokens, 4 waves. X tile + hidden chunk in LDS (bf16, XOR-swizzled).
// B operands (w1bf/w2bf) read straight from global (L2-resident, 2.4 MB).
// x1 lives in d_out; in-place safe (block-owned rows, read-before-write).
__global__ __launch_bounds__(256) void k_mlp(
    const float* __restrict__ x1, const u16* __restrict__ w1bf, const float* __restrict__ b1,
    const u16* __restrict__ w2bf, const float* __restrict__ b2,
    const float* __restrict__ n2g, const float* __restrict__ n2b,
    float* __restrict__ out){
  __shared__ char smem[65536];                 // xb 64x384 bf16 (49152) + hb 64x128 bf16 (16384)
  char* xb = smem;
  char* hb = smem + 49152;

  int tid  = threadIdx.x;
  int lane = tid & 63, wid = tid >> 6;
  int l15  = lane & 15, lg = lane >> 4;
  int wm = wid >> 1, wn = wid & 1;             // GEMM1 wave grid 2x2
  int gt0 = blockIdx.x * 64;

  // stage x1 tile -> bf16 swizzled LDS
  for (int e = tid; e < 64*48; e += 256){
    int r = e / 48, q8 = e - (e/48)*48;        // 8 floats per unit
    const float4* src = (const float4*)(x1 + (size_t)(gt0+r)*DIM + q8*8);
    float4 a = src[0], c = src[1];
    bf16x8 v;
    v[0]=(short)f2b(a.x); v[1]=(short)f2b(a.y); v[2]=(short)f2b(a.z); v[3]=(short)f2b(a.w);
    v[4]=(short)f2b(c.x); v[5]=(short)f2b(c.y); v[6]=(short)f2b(c.z); v[7]=(short)f2b(c.w);
    *(bf16x8*)(xb + r*768 + ((q8*16) ^ ((r&7)<<4))) = v;
  }

  f32x4 acc2[24];
  #pragma unroll
  for (int nf = 0; nf < 24; ++nf){
    float bb = b2[nf*16 + l15];
    acc2[nf] = (f32x4){bb, bb, bb, bb};
  }
  __syncthreads();                              // xb ready

  for (int hc = 0; hc < 1536; hc += 128){
    // ---- GEMM1: accH(32x64 per wave) = X(32x384) x W1chunk^T ----
    f32x4 accH[2][4];
    #pragma unroll
    for (int mf = 0; mf < 2; ++mf)
      #pragma unroll
      for (int nf = 0; nf < 4; ++nf)
        accH[mf][nf] = (f32x4){0.f,0.f,0.f,0.f};
    #pragma unroll 2
    for (int ksp = 0; ksp < 12; ++ksp){
      int k0 = ksp*32 + lg*8;
      bf16x8 afr[2];
      #pragma unroll
      for (int mf = 0; mf < 2; ++mf){
        int row = wm*32 + mf*16 + l15;
        afr[mf] = *(const bf16x8*)(xb + row*768 + ((k0*2) ^ ((row&7)<<4)));
      }
      #pragma unroll
      for (int nf = 0; nf < 4; ++nf){
        int col = hc + wn*64 + nf*16 + l15;
        bf16x8 bfr = *(const bf16x8*)(w1bf + (size_t)col*384 + k0);
        #pragma unroll
        for (int mf = 0; mf < 2; ++mf)
          accH[mf][nf] = __builtin_amdgcn_mfma_f32_16x16x32_bf16(afr[mf], bfr, accH[mf][nf], 0, 0, 0);
      }
    }
    __syncthreads();                            // prev GEMM2 hb reads complete
    // ---- bias + exact GELU -> hb (bf16 swizzled) ----
    #pragma unroll
    for (int mf = 0; mf < 2; ++mf)
      #pragma unroll
      for (int nf = 0; nf < 4; ++nf){
        int colh = wn*64 + nf*16 + l15;
        float bb1 = b1[hc + colh];
        #pragma unroll
        for (int r = 0; r < 4; ++r){
          float v = accH[mf][nf][r] + bb1;
          v = 0.5f*v*(1.f + erff(v*0.70710678f));
          int row = wm*32 + mf*16 + lg*4 + r;
          *(u16*)(hb + row*256 + ((colh*2) ^ ((row&7)<<4))) = f2b(v);
        }
      }
    __syncthreads();                            // hb visible
    // ---- GEMM2: acc2(16x384 per wave) += H(16x128) x W2chunk^T ----
    #pragma unroll
    for (int ksp = 0; ksp < 4; ++ksp){
      int k0 = ksp*32 + lg*8;
      int arow = wid*16 + l15;
      bf16x8 afr = *(const bf16x8*)(hb + arow*256 + ((k0*2) ^ ((arow&7)<<4)));
      #pragma unroll
      for (int nf = 0; nf < 24; ++nf){
        int col = nf*16 + l15;
        bf16x8 bfr = *(const bf16x8*)(w2bf + (size_t)col*1536 + hc + k0);
        acc2[nf] = __builtin_amdgcn_mfma_f32_16x16x32_bf16(afr, bfr, acc2[nf], 0, 0, 0);
      }
    }
  }

  // ---- LN2 + residual epilogue ----
  float s1[4] = {0.f,0.f,0.f,0.f}, s2[4] = {0.f,0.f,0.f,0.f};
  #pragma unroll
  for (int nf = 0; nf < 24; ++nf)
    #pragma unroll
    for (int r = 0; r < 4; ++r){
      float v = acc2[nf][r];
      s1[r] += v; s2[r] += v*v;
    }
  #pragma unroll
  for (int r = 0; r < 4; ++r){
    #pragma unroll
    for (int off = 1; off < 16; off <<= 1){
      s1[r] += __shfl_xor(s1[r], off, 64);
      s2[r] += __shfl_xor(s2[r], off, 64);
    }
  }
  #pragma unroll
  for (int r = 0; r < 4; ++r){
    float mu = s1[r]*(1.f/384.f);
    float rstd = rsqrtf(s2[r]*(1.f/384.f) - mu*mu + 1e-5f);
    int grow = gt0 + wid*16 + lg*4 + r;
    #pragma unroll
    for (int nf = 0; nf < 24; ++nf){
      int col = nf*16 + l15;
      float val = (acc2[nf][r]-mu)*rstd*n2g[col] + n2b[col] + x1[(size_t)grow*DIM + col];
      out[(size_t)grow*DIM + col] = val;
    }
  }
}

extern "C" void kernel_launch(void* const* d_in, const int* in_sizes, int n_in,
                              void* d_out, int out_size, void* d_ws, size_t ws_size,
                              hipStream_t stream){
  const float* x           = (const float*)d_in[0];
  const float* qkv_w       = (const float*)d_in[1];
  const float* q_bias      = (const float*)d_in[2];
  const float* v_bias      = (const float*)d_in[3];
  const float* logit_scale = (const float*)d_in[4];
  const float* cpb_w1      = (const float*)d_in[5];
  const float* cpb_b1      = (const float*)d_in[6];
  const float* cpb_w2      = (const float*)d_in[7];
  const float* proj_w      = (const float*)d_in[8];
  const float* proj_b      = (const float*)d_in[9];
  const float* n1g         = (const float*)d_in[10];
  const float* n1b         = (const float*)d_in[11];
  const float* n2g         = (const float*)d_in[12];
  const float* n2b         = (const float*)d_in[13];
  const float* mlp_w1      = (const float*)d_in[14];
  const float* mlp_b1      = (const float*)d_in[15];
  const float* mlp_w2      = (const float*)d_in[16];
  const float* mlp_b2      = (const float*)d_in[17];

  // ws: tab 8KB | outwin 77.07MB | w1bf 1.18MB | w2bf 1.18MB
  char* ws = (char*)d_ws;
  float* tab   = (float*)ws;
  u16*  outwin = (u16*)(ws + 8192);
  size_t owbytes = (size_t)NWIN*49*DIM*2;
  u16*  w1bf = (u16*)(ws + 8192 + owbytes);
  u16*  w2bf = (u16*)(ws + 8192 + owbytes + (size_t)1536*384*2);
  float* x1  = (float*)d_out;
  float* out = (float*)d_out;

  hipLaunchKernelGGL(k_bias, dim3(169), dim3(256), 0, stream, cpb_w1, cpb_b1, cpb_w2, tab);
  hipLaunchKernelGGL(k_wconv, dim3(1024), dim3(256), 0, stream, mlp_w1, mlp_w2, w1bf, w2bf);
  hipLaunchKernelGGL(k_attn, dim3(NWIN*NH), dim3(192), 0, stream,
                     x, qkv_w, q_bias, v_bias, logit_scale, tab, outwin);
  hipLaunchKernelGGL(k_proj, dim3(TOKENS/16), dim3(256), 0, stream,
                     outwin, proj_w, proj_b, x, n1g, n1b, x1);
  hipLaunchKernelGGL(k_mlp, dim3(TOKENS/64), dim3(256), 0, stream,
                     x1, w1bf, mlp_b1, w2bf, mlp_b2, n2g, n2b, out);
}

// Round 5
// 3056.277 us; speedup vs baseline: 3.1825x; 1.5263x over previous
//
#include <hip/hip_runtime.h>
#include <hip/hip_bf16.h>
#include <math.h>

#define DIM 384
#define NH 12
#define HD 32
#define NWIN 2048          // B * 64 windows
#define TOKENS 100352      // B * 56 * 56

typedef unsigned short u16;
typedef unsigned int u32;
typedef __attribute__((ext_vector_type(8))) short bf16x8;
typedef __attribute__((ext_vector_type(4))) float f32x4;

__device__ __forceinline__ float b2f(u16 u){ return __uint_as_float(((u32)u) << 16); }
__device__ __forceinline__ u16 f2b(float f){
  u32 x = __float_as_uint(f);
  return (u16)((x + 0x7FFFu + ((x >> 16) & 1u)) >> 16);   // RNE
}

// ---------------- weight pre-convert fp32 -> bf16 ----------------
__global__ void k_wconv(const float* __restrict__ w1, const float* __restrict__ w2,
                        const float* __restrict__ qw, const float* __restrict__ pw,
                        u16* __restrict__ w1bf, u16* __restrict__ w2bf,
                        u16* __restrict__ qwbf, u16* __restrict__ pwbf){
  const int n12 = 1536*384, n3 = 1152*384, n4 = 384*384;
  for (int i = blockIdx.x*blockDim.x + threadIdx.x; i < n12; i += gridDim.x*blockDim.x){
    w1bf[i] = f2b(w1[i]);
    w2bf[i] = f2b(w2[i]);
    if (i < n3) qwbf[i] = f2b(qw[i]);
    if (i < n4) pwbf[i] = f2b(pw[i]);
  }
}

// ---------------- CPB bias table: tab[169][12] ----------------
__global__ void k_bias(const float* __restrict__ w1, const float* __restrict__ b1,
                       const float* __restrict__ w2, float* __restrict__ tab){
  __shared__ float hid[512];
  int e = blockIdx.x;
  int i = e / 13, j = e % 13;
  float t0 = (float)(i - 6) * (8.0f / 6.0f);
  float t1 = (float)(j - 6) * (8.0f / 6.0f);
  t0 = copysignf(log2f(fabsf(t0) + 1.f) * (1.f / 3.f), t0);
  t1 = copysignf(log2f(fabsf(t1) + 1.f) * (1.f / 3.f), t1);
  for (int jj = threadIdx.x; jj < 512; jj += blockDim.x)
    hid[jj] = fmaxf(w1[jj*2]*t0 + w1[jj*2+1]*t1 + b1[jj], 0.f);
  __syncthreads();
  if (threadIdx.x < 12){
    float s = 0.f;
    for (int jj = 0; jj < 512; ++jj) s += hid[jj] * w2[threadIdx.x*512 + jj];
    tab[e*12 + threadIdx.x] = s;
  }
}

// ---------------- expand: biasfull[h][i*49+j] = 16*sigmoid(tab[rpi(i,j)][h]) ----------------
__global__ void k_bias2(const float* __restrict__ tab, float* __restrict__ biasfull){
  int h = blockIdx.x;
  for (int e = threadIdx.x; e < 49*49; e += blockDim.x){
    int i = e / 49, j = e - (e/49)*49;
    int ih = i/7, iw = i - ih*7, jh = j/7, jw = j - jh*7;
    float bv = tab[((ih-jh+6)*13 + (iw-jw+6))*12 + h];
    biasfull[h*2401 + e] = 16.f / (1.f + expf(-bv));
  }
}

// ---------------- fused QKV + cosine attention, one block per window ----------------
// 4 waves, 12-head loop. QKV / QK^T / PV all bf16 MFMA, fp32 accum.
__global__ __launch_bounds__(256) void k_attn(
    const float* __restrict__ x, const u16* __restrict__ qkvbf,
    const float* __restrict__ q_bias, const float* __restrict__ v_bias,
    const float* __restrict__ logit_scale, const float* __restrict__ biasfull,
    u16* __restrict__ outwin){
  __shared__ __align__(16) char smem[64000];
  char* xb = smem;                 // [64][768B] bf16, XOR-swizzled (16B granules)
  char* qn = smem + 49152;         // [64][80B] bf16 (stride 40 elems)
  char* kn = smem + 54272;         // [64][80B]
  char* pb = smem + 49152;         // alias qn+kn after QK^T: [64][144B] bf16
  char* vt = smem + 59392;         // [32][144B] bf16  (Vt[c][j])

  int tid  = threadIdx.x;
  int lane = tid & 63, wid = tid >> 6;
  int l15  = lane & 15, lg = lane >> 4;
  int win = blockIdx.x;
  int b = win >> 6, wi = win & 63;
  int wh = wi >> 3, ww = wi & 7;

  // stage rolled/windowed x tile -> bf16 swizzled LDS; rows 49..63 zero
  for (int e = tid; e < 64*48; e += 256){
    int r = e / 48, q8 = e - (e/48)*48;
    bf16x8 v = (bf16x8){0,0,0,0,0,0,0,0};
    if (r < 49){
      int th = r / 7, tw = r - th*7;
      int gh = wh*7 + th + 3; if (gh >= 56) gh -= 56;
      int gw = ww*7 + tw + 3; if (gw >= 56) gw -= 56;
      const float4* src = (const float4*)(x + ((size_t)(b*3136 + gh*56 + gw))*DIM + q8*8);
      float4 a = src[0], c = src[1];
      v[0]=(short)f2b(a.x); v[1]=(short)f2b(a.y); v[2]=(short)f2b(a.z); v[3]=(short)f2b(a.w);
      v[4]=(short)f2b(c.x); v[5]=(short)f2b(c.y); v[6]=(short)f2b(c.z); v[7]=(short)f2b(c.w);
    }
    *(bf16x8*)(xb + r*768 + ((q8*16) ^ ((r&7)<<4))) = v;
  }
  __syncthreads();

  for (int h = 0; h < NH; ++h){
    // ---- QKV GEMM: rows = wid*16 tile, cols n=nf*16+l15 (q:0-31,k:32-63,v:64-95) ----
    f32x4 acc[6];
    #pragma unroll
    for (int nf = 0; nf < 6; ++nf) acc[nf] = (f32x4){0.f,0.f,0.f,0.f};
    #pragma unroll 4
    for (int ksp = 0; ksp < 12; ++ksp){
      int k0 = ksp*32 + lg*8;
      int arow = wid*16 + l15;
      bf16x8 af = *(const bf16x8*)(xb + arow*768 + ((k0*2) ^ ((arow&7)<<4)));
      #pragma unroll
      for (int nf = 0; nf < 6; ++nf){
        int n = nf*16 + l15;
        int m = n >> 5, c = n & 31;
        bf16x8 bf = *(const bf16x8*)(qkvbf + (size_t)(m*DIM + h*HD + c)*DIM + k0);
        acc[nf] = __builtin_amdgcn_mfma_f32_16x16x32_bf16(af, bf, acc[nf], 0, 0, 0);
      }
    }
    // ---- bias + cosine norm (rows = wid*16+lg*4+r, cols spread over l15) ----
    float qb0 = q_bias[h*HD + l15], qb1 = q_bias[h*HD + 16 + l15];
    float vb0 = v_bias[h*HD + l15], vb1 = v_bias[h*HD + 16 + l15];
    float sc = expf(fminf(logit_scale[h], 4.6051702f));
    #pragma unroll
    for (int r = 0; r < 4; ++r){
      acc[0][r] += qb0; acc[1][r] += qb1;
      acc[4][r] += vb0; acc[5][r] += vb1;
      float sq = acc[0][r]*acc[0][r] + acc[1][r]*acc[1][r];
      float sk = acc[2][r]*acc[2][r] + acc[3][r]*acc[3][r];
      #pragma unroll
      for (int off = 1; off < 16; off <<= 1){
        sq += __shfl_xor(sq, off, 64);
        sk += __shfl_xor(sk, off, 64);
      }
      float rq = sc / fmaxf(sqrtf(sq), 1e-12f);
      float rk = 1.f / fmaxf(sqrtf(sk), 1e-12f);
      acc[0][r] *= rq; acc[1][r] *= rq;
      acc[2][r] *= rk; acc[3][r] *= rk;
    }
    // ---- write qn/kn (stride 40 bf16) + vt transposed (stride 72 bf16) ----
    #pragma unroll
    for (int r = 0; r < 4; ++r){
      int row = wid*16 + lg*4 + r;
      *(u16*)(qn + row*80 + l15*2)      = f2b(acc[0][r]);
      *(u16*)(qn + row*80 + 32 + l15*2) = f2b(acc[1][r]);
      *(u16*)(kn + row*80 + l15*2)      = f2b(acc[2][r]);
      *(u16*)(kn + row*80 + 32 + l15*2) = f2b(acc[3][r]);
      *(u16*)(vt + l15*144 + row*2)        = f2b(acc[4][r]);
      *(u16*)(vt + (16+l15)*144 + row*2)   = f2b(acc[5][r]);
    }
    __syncthreads();                           // qn/kn/vt visible
    // ---- QK^T: each wave rows wid*16, cols 0..63 (4 frags), K=32 ----
    f32x4 s[4];
    {
      int arow = wid*16 + l15;
      bf16x8 qa = *(const bf16x8*)(qn + arow*80 + lg*16);
      #pragma unroll
      for (int nf = 0; nf < 4; ++nf){
        int bcol = nf*16 + l15;
        bf16x8 kb = *(const bf16x8*)(kn + bcol*80 + lg*16);
        s[nf] = __builtin_amdgcn_mfma_f32_16x16x32_bf16(qa, kb,
                  (f32x4){0.f,0.f,0.f,0.f}, 0, 0, 0);
      }
    }
    __syncthreads();                           // qn/kn reads done -> pb writable
    // ---- bias + mask + softmax (rows i=wid*16+lg*4+r, cols j=nf*16+l15) ----
    #pragma unroll
    for (int nf = 0; nf < 4; ++nf){
      int j = nf*16 + l15;
      int jh = j/7, jw = j - jh*7;
      int ghj = wh*7+jh, gwj = ww*7+jw;
      int zj = (ghj<49?0:(ghj<53?1:2))*3 + (gwj<49?0:(gwj<53?1:2));
      #pragma unroll
      for (int r = 0; r < 4; ++r){
        int i = wid*16 + lg*4 + r;
        if (j < 49){
          int i2 = i < 49 ? i : 48;
          float add = biasfull[h*2401 + i2*49 + j];
          int ih = i2/7, iw = i2 - ih*7;
          int ghi = wh*7+ih, gwi = ww*7+iw;
          int zi = (ghi<49?0:(ghi<53?1:2))*3 + (gwi<49?0:(gwi<53?1:2));
          s[nf][r] += add + (zi != zj ? -100.f : 0.f);
        } else {
          s[nf][r] = -1e30f;
        }
      }
    }
    #pragma unroll
    for (int r = 0; r < 4; ++r){
      float m = fmaxf(fmaxf(s[0][r], s[1][r]), fmaxf(s[2][r], s[3][r]));
      #pragma unroll
      for (int off = 1; off < 16; off <<= 1) m = fmaxf(m, __shfl_xor(m, off, 64));
      float e0 = expf(s[0][r]-m), e1 = expf(s[1][r]-m);
      float e2 = expf(s[2][r]-m), e3 = expf(s[3][r]-m);
      float sum = e0+e1+e2+e3;
      #pragma unroll
      for (int off = 1; off < 16; off <<= 1) sum += __shfl_xor(sum, off, 64);
      float rs = 1.f/sum;
      s[0][r] = e0*rs; s[1][r] = e1*rs; s[2][r] = e2*rs; s[3][r] = e3*rs;
    }
    // ---- write P (bf16, stride 72) ----
    #pragma unroll
    for (int nf = 0; nf < 4; ++nf){
      int j = nf*16 + l15;
      #pragma unroll
      for (int r = 0; r < 4; ++r){
        int i = wid*16 + lg*4 + r;
        *(u16*)(pb + i*144 + j*2) = f2b(s[nf][r]);
      }
    }
    __syncthreads();                           // P visible
    // ---- PV: rows wid*16, cols c=nf*16+l15 (2 frags), K=64 ----
    f32x4 o[2];
    o[0] = (f32x4){0.f,0.f,0.f,0.f}; o[1] = o[0];
    #pragma unroll
    for (int ksp = 0; ksp < 2; ++ksp){
      int k0 = ksp*32 + lg*8;
      int prow = wid*16 + l15;
      bf16x8 pa = *(const bf16x8*)(pb + prow*144 + k0*2);
      #pragma unroll
      for (int nf = 0; nf < 2; ++nf){
        bf16x8 vb = *(const bf16x8*)(vt + (nf*16+l15)*144 + k0*2);
        o[nf] = __builtin_amdgcn_mfma_f32_16x16x32_bf16(pa, vb, o[nf], 0, 0, 0);
      }
    }
    #pragma unroll
    for (int r = 0; r < 4; ++r){
      int row = wid*16 + lg*4 + r;
      if (row < 49){
        size_t base = ((size_t)win*49 + row)*DIM + h*HD;
        outwin[base + l15]      = f2b(o[0][r]);
        outwin[base + 16 + l15] = f2b(o[1][r]);
      }
    }
    __syncthreads();                           // pv reads done -> next head may overwrite
  }
}

// ---------------- proj + window-reverse + LN1 + residual -> x1 (d_out), MFMA ----------------
__global__ __launch_bounds__(256) void k_proj(
    const u16* __restrict__ outwin, const u16* __restrict__ pwbf,
    const float* __restrict__ proj_b, const float* __restrict__ x,
    const float* __restrict__ n1g, const float* __restrict__ n1b,
    float* __restrict__ x1){
  __shared__ __align__(16) char sb[49152];     // 64x384 bf16 swizzled
  int tid  = threadIdx.x;
  int lane = tid & 63, wid = tid >> 6;
  int l15  = lane & 15, lg = lane >> 4;
  int gt0 = blockIdx.x * 64;

  for (int e = tid; e < 64*48; e += 256){      // gather (window-reverse) 64 token rows
    int r = e / 48, q8 = e - (e/48)*48;
    int gtok = gt0 + r;
    int b = gtok / 3136, r2 = gtok - b*3136;
    int oh = r2 / 56, ow = r2 - oh*56;
    int hs = oh + 53; if (hs >= 56) hs -= 56;
    int ws2 = ow + 53; if (ws2 >= 56) ws2 -= 56;
    int win = b*64 + (hs/7)*8 + (ws2/7);
    int row = (hs%7)*7 + (ws2%7);
    bf16x8 v = *(const bf16x8*)(outwin + ((size_t)win*49 + row)*DIM + q8*8);
    *(bf16x8*)(sb + r*768 + ((q8*16) ^ ((r&7)<<4))) = v;
  }
  f32x4 acc[24];
  #pragma unroll
  for (int nf = 0; nf < 24; ++nf){
    float pbv = proj_b[nf*16 + l15];
    acc[nf] = (f32x4){pbv, pbv, pbv, pbv};
  }
  __syncthreads();
  #pragma unroll 2
  for (int ksp = 0; ksp < 12; ++ksp){
    int k0 = ksp*32 + lg*8;
    int arow = wid*16 + l15;
    bf16x8 af = *(const bf16x8*)(sb + arow*768 + ((k0*2) ^ ((arow&7)<<4)));
    #pragma unroll
    for (int nf = 0; nf < 24; ++nf){
      bf16x8 bf = *(const bf16x8*)(pwbf + (size_t)(nf*16+l15)*DIM + k0);
      acc[nf] = __builtin_amdgcn_mfma_f32_16x16x32_bf16(af, bf, acc[nf], 0, 0, 0);
    }
  }
  // ---- LN1 + residual epilogue ----
  float s1[4] = {0.f,0.f,0.f,0.f}, s2[4] = {0.f,0.f,0.f,0.f};
  #pragma unroll
  for (int nf = 0; nf < 24; ++nf)
    #pragma unroll
    for (int r = 0; r < 4; ++r){
      float v = acc[nf][r];
      s1[r] += v; s2[r] += v*v;
    }
  #pragma unroll
  for (int r = 0; r < 4; ++r){
    #pragma unroll
    for (int off = 1; off < 16; off <<= 1){
      s1[r] += __shfl_xor(s1[r], off, 64);
      s2[r] += __shfl_xor(s2[r], off, 64);
    }
  }
  #pragma unroll
  for (int r = 0; r < 4; ++r){
    float mu = s1[r]*(1.f/384.f);
    float rstd = rsqrtf(s2[r]*(1.f/384.f) - mu*mu + 1e-5f);
    int grow = gt0 + wid*16 + lg*4 + r;
    #pragma unroll
    for (int nf = 0; nf < 24; ++nf){
      int col = nf*16 + l15;
      x1[(size_t)grow*DIM + col] =
          (acc[nf][r]-mu)*rstd*n1g[col] + n1b[col] + x[(size_t)grow*DIM + col];
    }
  }
}

// ---------------- fused MLP via bf16 MFMA + LN2 + residual (unchanged) ----------------
__global__ __launch_bounds__(256) void k_mlp(
    const float* __restrict__ x1, const u16* __restrict__ w1bf, const float* __restrict__ b1,
    const u16* __restrict__ w2bf, const float* __restrict__ b2,
    const float* __restrict__ n2g, const float* __restrict__ n2b,
    float* __restrict__ out){
  __shared__ char smem[65536];
  char* xb = smem;
  char* hb = smem + 49152;

  int tid  = threadIdx.x;
  int lane = tid & 63, wid = tid >> 6;
  int l15  = lane & 15, lg = lane >> 4;
  int wm = wid >> 1, wn = wid & 1;
  int gt0 = blockIdx.x * 64;

  for (int e = tid; e < 64*48; e += 256){
    int r = e / 48, q8 = e - (e/48)*48;
    const float4* src = (const float4*)(x1 + (size_t)(gt0+r)*DIM + q8*8);
    float4 a = src[0], c = src[1];
    bf16x8 v;
    v[0]=(short)f2b(a.x); v[1]=(short)f2b(a.y); v[2]=(short)f2b(a.z); v[3]=(short)f2b(a.w);
    v[4]=(short)f2b(c.x); v[5]=(short)f2b(c.y); v[6]=(short)f2b(c.z); v[7]=(short)f2b(c.w);
    *(bf16x8*)(xb + r*768 + ((q8*16) ^ ((r&7)<<4))) = v;
  }

  f32x4 acc2[24];
  #pragma unroll
  for (int nf = 0; nf < 24; ++nf){
    float bb = b2[nf*16 + l15];
    acc2[nf] = (f32x4){bb, bb, bb, bb};
  }
  __syncthreads();

  for (int hc = 0; hc < 1536; hc += 128){
    f32x4 accH[2][4];
    #pragma unroll
    for (int mf = 0; mf < 2; ++mf)
      #pragma unroll
      for (int nf = 0; nf < 4; ++nf)
        accH[mf][nf] = (f32x4){0.f,0.f,0.f,0.f};
    #pragma unroll 2
    for (int ksp = 0; ksp < 12; ++ksp){
      int k0 = ksp*32 + lg*8;
      bf16x8 afr[2];
      #pragma unroll
      for (int mf = 0; mf < 2; ++mf){
        int row = wm*32 + mf*16 + l15;
        afr[mf] = *(const bf16x8*)(xb + row*768 + ((k0*2) ^ ((row&7)<<4)));
      }
      #pragma unroll
      for (int nf = 0; nf < 4; ++nf){
        int col = hc + wn*64 + nf*16 + l15;
        bf16x8 bfr = *(const bf16x8*)(w1bf + (size_t)col*384 + k0);
        #pragma unroll
        for (int mf = 0; mf < 2; ++mf)
          accH[mf][nf] = __builtin_amdgcn_mfma_f32_16x16x32_bf16(afr[mf], bfr, accH[mf][nf], 0, 0, 0);
      }
    }
    __syncthreads();
    #pragma unroll
    for (int mf = 0; mf < 2; ++mf)
      #pragma unroll
      for (int nf = 0; nf < 4; ++nf){
        int colh = wn*64 + nf*16 + l15;
        float bb1 = b1[hc + colh];
        #pragma unroll
        for (int r = 0; r < 4; ++r){
          float v = accH[mf][nf][r] + bb1;
          v = 0.5f*v*(1.f + erff(v*0.70710678f));
          int row = wm*32 + mf*16 + lg*4 + r;
          *(u16*)(hb + row*256 + ((colh*2) ^ ((row&7)<<4))) = f2b(v);
        }
      }
    __syncthreads();
    #pragma unroll
    for (int ksp = 0; ksp < 4; ++ksp){
      int k0 = ksp*32 + lg*8;
      int arow = wid*16 + l15;
      bf16x8 afr = *(const bf16x8*)(hb + arow*256 + ((k0*2) ^ ((arow&7)<<4)));
      #pragma unroll
      for (int nf = 0; nf < 24; ++nf){
        int col = nf*16 + l15;
        bf16x8 bfr = *(const bf16x8*)(w2bf + (size_t)col*1536 + hc + k0);
        acc2[nf] = __builtin_amdgcn_mfma_f32_16x16x32_bf16(afr, bfr, acc2[nf], 0, 0, 0);
      }
    }
  }

  float s1[4] = {0.f,0.f,0.f,0.f}, s2[4] = {0.f,0.f,0.f,0.f};
  #pragma unroll
  for (int nf = 0; nf < 24; ++nf)
    #pragma unroll
    for (int r = 0; r < 4; ++r){
      float v = acc2[nf][r];
      s1[r] += v; s2[r] += v*v;
    }
  #pragma unroll
  for (int r = 0; r < 4; ++r){
    #pragma unroll
    for (int off = 1; off < 16; off <<= 1){
      s1[r] += __shfl_xor(s1[r], off, 64);
      s2[r] += __shfl_xor(s2[r], off, 64);
    }
  }
  #pragma unroll
  for (int r = 0; r < 4; ++r){
    float mu = s1[r]*(1.f/384.f);
    float rstd = rsqrtf(s2[r]*(1.f/384.f) - mu*mu + 1e-5f);
    int grow = gt0 + wid*16 + lg*4 + r;
    #pragma unroll
    for (int nf = 0; nf < 24; ++nf){
      int col = nf*16 + l15;
      float val = (acc2[nf][r]-mu)*rstd*n2g[col] + n2b[col] + x1[(size_t)grow*DIM + col];
      out[(size_t)grow*DIM + col] = val;
    }
  }
}

extern "C" void kernel_launch(void* const* d_in, const int* in_sizes, int n_in,
                              void* d_out, int out_size, void* d_ws, size_t ws_size,
                              hipStream_t stream){
  const float* x           = (const float*)d_in[0];
  const float* qkv_w       = (const float*)d_in[1];
  const float* q_bias      = (const float*)d_in[2];
  const float* v_bias      = (const float*)d_in[3];
  const float* logit_scale = (const float*)d_in[4];
  const float* cpb_w1      = (const float*)d_in[5];
  const float* cpb_b1      = (const float*)d_in[6];
  const float* cpb_w2      = (const float*)d_in[7];
  const float* proj_w      = (const float*)d_in[8];
  const float* proj_b      = (const float*)d_in[9];
  const float* n1g         = (const float*)d_in[10];
  const float* n1b         = (const float*)d_in[11];
  const float* n2g         = (const float*)d_in[12];
  const float* n2b         = (const float*)d_in[13];
  const float* mlp_w1      = (const float*)d_in[14];
  const float* mlp_b1      = (const float*)d_in[15];
  const float* mlp_w2      = (const float*)d_in[16];
  const float* mlp_b2      = (const float*)d_in[17];

  // ws: tab 8K | biasfull 116K | outwin 77.07M | qkvbf .88M | pwbf .29M | w1bf 1.18M | w2bf 1.18M
  char* ws = (char*)d_ws;
  float* tab      = (float*)ws;
  float* biasfull = (float*)(ws + 8192);
  u16*  outwin = (u16*)(ws + 126976);
  u16*  qkvbf  = (u16*)(ws + 126976 + 77070336ull);
  u16*  pwbf   = (u16*)(ws + 126976 + 77070336ull + 884736ull);
  u16*  w1bf   = (u16*)(ws + 126976 + 77070336ull + 884736ull + 294912ull);
  u16*  w2bf   = (u16*)(ws + 126976 + 77070336ull + 884736ull + 294912ull + 1179648ull);
  float* x1  = (float*)d_out;
  float* out = (float*)d_out;

  hipLaunchKernelGGL(k_bias, dim3(169), dim3(256), 0, stream, cpb_w1, cpb_b1, cpb_w2, tab);
  hipLaunchKernelGGL(k_bias2, dim3(12), dim3(256), 0, stream, tab, biasfull);
  hipLaunchKernelGGL(k_wconv, dim3(1024), dim3(256), 0, stream,
                     mlp_w1, mlp_w2, qkv_w, proj_w, w1bf, w2bf, qkvbf, pwbf);
  hipLaunchKernelGGL(k_attn, dim3(NWIN), dim3(256), 0, stream,
                     x, qkvbf, q_bias, v_bias, logit_scale, biasfull, outwin);
  hipLaunchKernelGGL(k_proj, dim3(TOKENS/64), dim3(256), 0, stream,
                     outwin, pwbf, proj_b, x, n1g, n1b, x1);
  hipLaunchKernelGGL(k_mlp, dim3(TOKENS/64), dim3(256), 0, stream,
                     x1, w1bf, mlp_b1, w2bf, mlp_b2, n2g, n2b, out);
}

// Round 6
// 2031.107 us; speedup vs baseline: 4.7889x; 1.5047x over previous
//
#include <hip/hip_runtime.h>
#include <hip/hip_bf16.h>
#include <math.h>

#define DIM 384
#define NH 12
#define HD 32
#define NWIN 2048          // B * 64 windows
#define TOKENS 100352      // B * 56 * 56

typedef unsigned short u16;
typedef unsigned int u32;
typedef __attribute__((ext_vector_type(8))) short bf16x8;
typedef __attribute__((ext_vector_type(4))) float f32x4;

__device__ __forceinline__ float b2f(u16 u){ return __uint_as_float(((u32)u) << 16); }
__device__ __forceinline__ u16 f2b(float f){
  u32 x = __float_as_uint(f);
  return (u16)((x + 0x7FFFu + ((x >> 16) & 1u)) >> 16);   // RNE
}

// ---------------- weight pre-convert fp32 -> bf16 ----------------
__global__ void k_wconv(const float* __restrict__ w1, const float* __restrict__ w2,
                        const float* __restrict__ qw, const float* __restrict__ pw,
                        u16* __restrict__ w1bf, u16* __restrict__ w2bf,
                        u16* __restrict__ qwbf, u16* __restrict__ pwbf){
  const int n12 = 1536*384, n3 = 1152*384, n4 = 384*384;
  for (int i = blockIdx.x*blockDim.x + threadIdx.x; i < n12; i += gridDim.x*blockDim.x){
    w1bf[i] = f2b(w1[i]);
    w2bf[i] = f2b(w2[i]);
    if (i < n3) qwbf[i] = f2b(qw[i]);
    if (i < n4) pwbf[i] = f2b(pw[i]);
  }
}

// ---------------- CPB bias table: tab[169][12] ----------------
__global__ void k_bias(const float* __restrict__ w1, const float* __restrict__ b1,
                       const float* __restrict__ w2, float* __restrict__ tab){
  __shared__ float hid[512];
  int e = blockIdx.x;
  int i = e / 13, j = e % 13;
  float t0 = (float)(i - 6) * (8.0f / 6.0f);
  float t1 = (float)(j - 6) * (8.0f / 6.0f);
  t0 = copysignf(log2f(fabsf(t0) + 1.f) * (1.f / 3.f), t0);
  t1 = copysignf(log2f(fabsf(t1) + 1.f) * (1.f / 3.f), t1);
  for (int jj = threadIdx.x; jj < 512; jj += blockDim.x)
    hid[jj] = fmaxf(w1[jj*2]*t0 + w1[jj*2+1]*t1 + b1[jj], 0.f);
  __syncthreads();
  if (threadIdx.x < 12){
    float s = 0.f;
    for (int jj = 0; jj < 512; ++jj) s += hid[jj] * w2[threadIdx.x*512 + jj];
    tab[e*12 + threadIdx.x] = s;
  }
}

// ---------------- expand: biasfull[h][i*49+j] = 16*sigmoid(tab[rpi(i,j)][h]) ----------------
__global__ void k_bias2(const float* __restrict__ tab, float* __restrict__ biasfull){
  int h = blockIdx.x;
  for (int e = threadIdx.x; e < 49*49; e += blockDim.x){
    int i = e / 49, j = e - (e/49)*49;
    int ih = i/7, iw = i - ih*7, jh = j/7, jw = j - jh*7;
    float bv = tab[((ih-jh+6)*13 + (iw-jw+6))*12 + h];
    biasfull[h*2401 + e] = 16.f / (1.f + expf(-bv));
  }
}

// ---------------- fused QKV + cosine attention, one block per window ----------------
__global__ __launch_bounds__(256) void k_attn(
    const float* __restrict__ x, const u16* __restrict__ qkvbf,
    const float* __restrict__ q_bias, const float* __restrict__ v_bias,
    const float* __restrict__ logit_scale, const float* __restrict__ biasfull,
    u16* __restrict__ outwin){
  __shared__ __align__(16) char smem[64000];
  char* xb = smem;                 // [64][768B] bf16, XOR-swizzled (16B granules)
  char* qn = smem + 49152;         // [64][80B] bf16 (stride 40 elems)
  char* kn = smem + 54272;         // [64][80B]
  char* pb = smem + 49152;         // alias qn+kn after QK^T: [64][144B] bf16
  char* vt = smem + 59392;         // [32][144B] bf16  (Vt[c][j])

  int tid  = threadIdx.x;
  int lane = tid & 63, wid = tid >> 6;
  int l15  = lane & 15, lg = lane >> 4;
  int win = blockIdx.x;
  int b = win >> 6, wi = win & 63;
  int wh = wi >> 3, ww = wi & 7;

  // stage rolled/windowed x tile -> bf16 swizzled LDS; rows 49..63 zero
  for (int e = tid; e < 64*48; e += 256){
    int r = e / 48, q8 = e - (e/48)*48;
    bf16x8 v = (bf16x8){0,0,0,0,0,0,0,0};
    if (r < 49){
      int th = r / 7, tw = r - th*7;
      int gh = wh*7 + th + 3; if (gh >= 56) gh -= 56;
      int gw = ww*7 + tw + 3; if (gw >= 56) gw -= 56;
      const float4* src = (const float4*)(x + ((size_t)(b*3136 + gh*56 + gw))*DIM + q8*8);
      float4 a = src[0], c = src[1];
      v[0]=(short)f2b(a.x); v[1]=(short)f2b(a.y); v[2]=(short)f2b(a.z); v[3]=(short)f2b(a.w);
      v[4]=(short)f2b(c.x); v[5]=(short)f2b(c.y); v[6]=(short)f2b(c.z); v[7]=(short)f2b(c.w);
    }
    *(bf16x8*)(xb + r*768 + ((q8*16) ^ ((r&7)<<4))) = v;
  }
  __syncthreads();

  for (int h = 0; h < NH; ++h){
    // ---- QKV GEMM: rows = wid*16 tile, cols n=nf*16+l15 (q:0-31,k:32-63,v:64-95) ----
    f32x4 acc[6];
    #pragma unroll
    for (int nf = 0; nf < 6; ++nf) acc[nf] = (f32x4){0.f,0.f,0.f,0.f};
    #pragma unroll 4
    for (int ksp = 0; ksp < 12; ++ksp){
      int k0 = ksp*32 + lg*8;
      int arow = wid*16 + l15;
      bf16x8 af = *(const bf16x8*)(xb + arow*768 + ((k0*2) ^ ((arow&7)<<4)));
      #pragma unroll
      for (int nf = 0; nf < 6; ++nf){
        int n = nf*16 + l15;
        int m = n >> 5, c = n & 31;
        bf16x8 bf = *(const bf16x8*)(qkvbf + (size_t)(m*DIM + h*HD + c)*DIM + k0);
        acc[nf] = __builtin_amdgcn_mfma_f32_16x16x32_bf16(af, bf, acc[nf], 0, 0, 0);
      }
    }
    // ---- bias + cosine norm ----
    float qb0 = q_bias[h*HD + l15], qb1 = q_bias[h*HD + 16 + l15];
    float vb0 = v_bias[h*HD + l15], vb1 = v_bias[h*HD + 16 + l15];
    float sc = expf(fminf(logit_scale[h], 4.6051702f));
    #pragma unroll
    for (int r = 0; r < 4; ++r){
      acc[0][r] += qb0; acc[1][r] += qb1;
      acc[4][r] += vb0; acc[5][r] += vb1;
      float sq = acc[0][r]*acc[0][r] + acc[1][r]*acc[1][r];
      float sk = acc[2][r]*acc[2][r] + acc[3][r]*acc[3][r];
      #pragma unroll
      for (int off = 1; off < 16; off <<= 1){
        sq += __shfl_xor(sq, off, 64);
        sk += __shfl_xor(sk, off, 64);
      }
      float rq = sc / fmaxf(sqrtf(sq), 1e-12f);
      float rk = 1.f / fmaxf(sqrtf(sk), 1e-12f);
      acc[0][r] *= rq; acc[1][r] *= rq;
      acc[2][r] *= rk; acc[3][r] *= rk;
    }
    // ---- write qn/kn (stride 40 bf16) + vt transposed (stride 72 bf16) ----
    #pragma unroll
    for (int r = 0; r < 4; ++r){
      int row = wid*16 + lg*4 + r;
      *(u16*)(qn + row*80 + l15*2)      = f2b(acc[0][r]);
      *(u16*)(qn + row*80 + 32 + l15*2) = f2b(acc[1][r]);
      *(u16*)(kn + row*80 + l15*2)      = f2b(acc[2][r]);
      *(u16*)(kn + row*80 + 32 + l15*2) = f2b(acc[3][r]);
      *(u16*)(vt + l15*144 + row*2)        = f2b(acc[4][r]);
      *(u16*)(vt + (16+l15)*144 + row*2)   = f2b(acc[5][r]);
    }
    __syncthreads();                           // qn/kn/vt visible
    // ---- QK^T ----
    f32x4 s[4];
    {
      int arow = wid*16 + l15;
      bf16x8 qa = *(const bf16x8*)(qn + arow*80 + lg*16);
      #pragma unroll
      for (int nf = 0; nf < 4; ++nf){
        int bcol = nf*16 + l15;
        bf16x8 kb = *(const bf16x8*)(kn + bcol*80 + lg*16);
        s[nf] = __builtin_amdgcn_mfma_f32_16x16x32_bf16(qa, kb,
                  (f32x4){0.f,0.f,0.f,0.f}, 0, 0, 0);
      }
    }
    __syncthreads();                           // qn/kn reads done -> pb writable
    // ---- bias + mask + softmax ----
    #pragma unroll
    for (int nf = 0; nf < 4; ++nf){
      int j = nf*16 + l15;
      int jh = j/7, jw = j - jh*7;
      int ghj = wh*7+jh, gwj = ww*7+jw;
      int zj = (ghj<49?0:(ghj<53?1:2))*3 + (gwj<49?0:(gwj<53?1:2));
      #pragma unroll
      for (int r = 0; r < 4; ++r){
        int i = wid*16 + lg*4 + r;
        if (j < 49){
          int i2 = i < 49 ? i : 48;
          float add = biasfull[h*2401 + i2*49 + j];
          int ih = i2/7, iw = i2 - ih*7;
          int ghi = wh*7+ih, gwi = ww*7+iw;
          int zi = (ghi<49?0:(ghi<53?1:2))*3 + (gwi<49?0:(gwi<53?1:2));
          s[nf][r] += add + (zi != zj ? -100.f : 0.f);
        } else {
          s[nf][r] = -1e30f;
        }
      }
    }
    #pragma unroll
    for (int r = 0; r < 4; ++r){
      float m = fmaxf(fmaxf(s[0][r], s[1][r]), fmaxf(s[2][r], s[3][r]));
      #pragma unroll
      for (int off = 1; off < 16; off <<= 1) m = fmaxf(m, __shfl_xor(m, off, 64));
      float e0 = expf(s[0][r]-m), e1 = expf(s[1][r]-m);
      float e2 = expf(s[2][r]-m), e3 = expf(s[3][r]-m);
      float sum = e0+e1+e2+e3;
      #pragma unroll
      for (int off = 1; off < 16; off <<= 1) sum += __shfl_xor(sum, off, 64);
      float rs = 1.f/sum;
      s[0][r] = e0*rs; s[1][r] = e1*rs; s[2][r] = e2*rs; s[3][r] = e3*rs;
    }
    // ---- write P (bf16, stride 72) ----
    #pragma unroll
    for (int nf = 0; nf < 4; ++nf){
      int j = nf*16 + l15;
      #pragma unroll
      for (int r = 0; r < 4; ++r){
        int i = wid*16 + lg*4 + r;
        *(u16*)(pb + i*144 + j*2) = f2b(s[nf][r]);
      }
    }
    __syncthreads();                           // P visible
    // ---- PV ----
    f32x4 o[2];
    o[0] = (f32x4){0.f,0.f,0.f,0.f}; o[1] = o[0];
    #pragma unroll
    for (int ksp = 0; ksp < 2; ++ksp){
      int k0 = ksp*32 + lg*8;
      int prow = wid*16 + l15;
      bf16x8 pa = *(const bf16x8*)(pb + prow*144 + k0*2);
      #pragma unroll
      for (int nf = 0; nf < 2; ++nf){
        bf16x8 vb = *(const bf16x8*)(vt + (nf*16+l15)*144 + k0*2);
        o[nf] = __builtin_amdgcn_mfma_f32_16x16x32_bf16(pa, vb, o[nf], 0, 0, 0);
      }
    }
    #pragma unroll
    for (int r = 0; r < 4; ++r){
      int row = wid*16 + lg*4 + r;
      if (row < 49){
        size_t base = ((size_t)win*49 + row)*DIM + h*HD;
        outwin[base + l15]      = f2b(o[0][r]);
        outwin[base + 16 + l15] = f2b(o[1][r]);
      }
    }
    __syncthreads();                           // pv reads done -> next head may overwrite
  }
}

// ---------------- proj + window-reverse + LN1 + residual -> x1 (d_out), MFMA ----------------
__global__ __launch_bounds__(256) void k_proj(
    const u16* __restrict__ outwin, const u16* __restrict__ pwbf,
    const float* __restrict__ proj_b, const float* __restrict__ x,
    const float* __restrict__ n1g, const float* __restrict__ n1b,
    float* __restrict__ x1){
  __shared__ __align__(16) char sb[49152];     // 64x384 bf16 swizzled
  int tid  = threadIdx.x;
  int lane = tid & 63, wid = tid >> 6;
  int l15  = lane & 15, lg = lane >> 4;
  int gt0 = blockIdx.x * 64;

  for (int e = tid; e < 64*48; e += 256){      // gather (window-reverse) 64 token rows
    int r = e / 48, q8 = e - (e/48)*48;
    int gtok = gt0 + r;
    int b = gtok / 3136, r2 = gtok - b*3136;
    int oh = r2 / 56, ow = r2 - oh*56;
    int hs = oh + 53; if (hs >= 56) hs -= 56;
    int ws2 = ow + 53; if (ws2 >= 56) ws2 -= 56;
    int win = b*64 + (hs/7)*8 + (ws2/7);
    int row = (hs%7)*7 + (ws2%7);
    bf16x8 v = *(const bf16x8*)(outwin + ((size_t)win*49 + row)*DIM + q8*8);
    *(bf16x8*)(sb + r*768 + ((q8*16) ^ ((r&7)<<4))) = v;
  }
  f32x4 acc[24];
  #pragma unroll
  for (int nf = 0; nf < 24; ++nf){
    float pbv = proj_b[nf*16 + l15];
    acc[nf] = (f32x4){pbv, pbv, pbv, pbv};
  }
  __syncthreads();
  #pragma unroll 2
  for (int ksp = 0; ksp < 12; ++ksp){
    int k0 = ksp*32 + lg*8;
    int arow = wid*16 + l15;
    bf16x8 af = *(const bf16x8*)(sb + arow*768 + ((k0*2) ^ ((arow&7)<<4)));
    #pragma unroll
    for (int nf = 0; nf < 24; ++nf){
      bf16x8 bf = *(const bf16x8*)(pwbf + (size_t)(nf*16+l15)*DIM + k0);
      acc[nf] = __builtin_amdgcn_mfma_f32_16x16x32_bf16(af, bf, acc[nf], 0, 0, 0);
    }
  }
  // ---- LN1 + residual epilogue ----
  float s1[4] = {0.f,0.f,0.f,0.f}, s2[4] = {0.f,0.f,0.f,0.f};
  #pragma unroll
  for (int nf = 0; nf < 24; ++nf)
    #pragma unroll
    for (int r = 0; r < 4; ++r){
      float v = acc[nf][r];
      s1[r] += v; s2[r] += v*v;
    }
  #pragma unroll
  for (int r = 0; r < 4; ++r){
    #pragma unroll
    for (int off = 1; off < 16; off <<= 1){
      s1[r] += __shfl_xor(s1[r], off, 64);
      s2[r] += __shfl_xor(s2[r], off, 64);
    }
  }
  #pragma unroll
  for (int r = 0; r < 4; ++r){
    float mu = s1[r]*(1.f/384.f);
    float rstd = rsqrtf(s2[r]*(1.f/384.f) - mu*mu + 1e-5f);
    int grow = gt0 + wid*16 + lg*4 + r;
    #pragma unroll
    for (int nf = 0; nf < 24; ++nf){
      int col = nf*16 + l15;
      x1[(size_t)grow*DIM + col] =
          (acc[nf][r]-mu)*rstd*n1g[col] + n1b[col] + x[(size_t)grow*DIM + col];
    }
  }
}

// ---------------- fused MLP v3: 512 thr / 8 waves, 64 tokens/block ----------------
// GEMM1: 2m x 4n wave grid (wave: 32 rows x 32 cols of the 128-wide hidden chunk).
// GEMM2: 8-way col split (wave: 64 rows x 48 cols, nf = wid, wid+8, wid+16).
// No B-fragment redundancy across waves; acc2[4][3]+accH[2][2] keep VGPR <= 128
// so __launch_bounds__(512,4) gives 4 waves/SIMD (2x round-5 occupancy).
__global__ __launch_bounds__(512, 4) void k_mlp(
    const float* __restrict__ x1, const u16* __restrict__ w1bf, const float* __restrict__ b1,
    const u16* __restrict__ w2bf, const float* __restrict__ b2,
    const float* __restrict__ n2g, const float* __restrict__ n2b,
    float* __restrict__ out){
  __shared__ __align__(16) char smem[65536];
  char* xb = smem;                 // [64][768B] bf16, swz ^((row&15)<<4)
  char* hb = smem + 49152;         // [64][256B] bf16, swz ^((row&15)<<4)

  int tid  = threadIdx.x;
  int lane = tid & 63, wid = tid >> 6;        // 8 waves
  int l15  = lane & 15, lg = lane >> 4;
  int wm = wid >> 2, wn = wid & 3;            // GEMM1 grid 2m x 4n
  int gt0 = blockIdx.x * 64;

  // stage x1 tile -> bf16 swizzled LDS
  for (int e = tid; e < 64*48; e += 512){
    int r = e / 48, q8 = e - (e/48)*48;
    const float4* src = (const float4*)(x1 + (size_t)(gt0+r)*DIM + q8*8);
    float4 a = src[0], c = src[1];
    bf16x8 v;
    v[0]=(short)f2b(a.x); v[1]=(short)f2b(a.y); v[2]=(short)f2b(a.z); v[3]=(short)f2b(a.w);
    v[4]=(short)f2b(c.x); v[5]=(short)f2b(c.y); v[6]=(short)f2b(c.z); v[7]=(short)f2b(c.w);
    *(bf16x8*)(xb + r*768 + ((q8*16) ^ ((r&15)<<4))) = v;
  }

  f32x4 acc2[4][3];
  #pragma unroll
  for (int mf = 0; mf < 4; ++mf)
    #pragma unroll
    for (int t = 0; t < 3; ++t){
      float bb = b2[(wid + 8*t)*16 + l15];
      acc2[mf][t] = (f32x4){bb, bb, bb, bb};
    }
  __syncthreads();                             // xb ready

  for (int hc = 0; hc < 1536; hc += 128){
    // ---- GEMM1: accH = X(32x384) x W1chunk^T(32 cols) ----
    f32x4 accH[2][2];
    #pragma unroll
    for (int mf = 0; mf < 2; ++mf)
      #pragma unroll
      for (int nh = 0; nh < 2; ++nh){
        float bb = b1[hc + wn*32 + nh*16 + l15];
        accH[mf][nh] = (f32x4){bb, bb, bb, bb};
      }
    #pragma unroll 2
    for (int ksp = 0; ksp < 12; ++ksp){
      int k0 = ksp*32 + lg*8;
      bf16x8 afr[2], bfr[2];
      #pragma unroll
      for (int mf = 0; mf < 2; ++mf){
        int row = wm*32 + mf*16 + l15;
        afr[mf] = *(const bf16x8*)(xb + row*768 + ((k0*2) ^ ((row&15)<<4)));
      }
      #pragma unroll
      for (int nh = 0; nh < 2; ++nh)
        bfr[nh] = *(const bf16x8*)(w1bf + (size_t)(hc + wn*32 + nh*16 + l15)*384 + k0);
      #pragma unroll
      for (int mf = 0; mf < 2; ++mf)
        #pragma unroll
        for (int nh = 0; nh < 2; ++nh)
          accH[mf][nh] = __builtin_amdgcn_mfma_f32_16x16x32_bf16(afr[mf], bfr[nh], accH[mf][nh], 0, 0, 0);
    }
    // ---- exact GELU -> hb ----
    #pragma unroll
    for (int mf = 0; mf < 2; ++mf)
      #pragma unroll
      for (int nh = 0; nh < 2; ++nh)
        #pragma unroll
        for (int r = 0; r < 4; ++r){
          float v = accH[mf][nh][r];
          v = 0.5f*v*(1.f + erff(v*0.70710678f));
          int row = wm*32 + mf*16 + lg*4 + r;
          int col = wn*32 + nh*16 + l15;
          *(u16*)(hb + row*256 + ((col*2) ^ ((row&15)<<4))) = f2b(v);
        }
    __syncthreads();                           // hb visible
    // ---- GEMM2: acc2 += H(64x128) x W2chunk^T (wave's 48 cols) ----
    #pragma unroll
    for (int ks = 0; ks < 4; ++ks){
      int k0 = ks*32 + lg*8;
      bf16x8 pa[4];
      #pragma unroll
      for (int mf = 0; mf < 4; ++mf){
        int row = mf*16 + l15;
        pa[mf] = *(const bf16x8*)(hb + row*256 + ((k0*2) ^ ((row&15)<<4)));
      }
      #pragma unroll
      for (int t = 0; t < 3; ++t){
        bf16x8 pbt = *(const bf16x8*)(w2bf + (size_t)((wid + 8*t)*16 + l15)*1536 + hc + k0);
        #pragma unroll
        for (int mf = 0; mf < 4; ++mf)
          acc2[mf][t] = __builtin_amdgcn_mfma_f32_16x16x32_bf16(pa[mf], pbt, acc2[mf][t], 0, 0, 0);
      }
    }
    __syncthreads();                           // hb reads done before next GELU overwrite
  }

  // ---- LN2 (cross-wave via LDS) + residual epilogue ----
  float* part = (float*)hb;                    // [64][8][2] f32 = 4 KB (hb dead)
  float* lnf  = (float*)(hb + 4096);           // [64][2]
  float s1a[4][4], s2a[4][4];
  #pragma unroll
  for (int mf = 0; mf < 4; ++mf)
    #pragma unroll
    for (int r = 0; r < 4; ++r){
      float p1 = acc2[mf][0][r] + acc2[mf][1][r] + acc2[mf][2][r];
      float p2 = acc2[mf][0][r]*acc2[mf][0][r] + acc2[mf][1][r]*acc2[mf][1][r]
               + acc2[mf][2][r]*acc2[mf][2][r];
      #pragma unroll
      for (int off = 1; off < 16; off <<= 1){
        p1 += __shfl_xor(p1, off, 64);
        p2 += __shfl_xor(p2, off, 64);
      }
      s1a[mf][r] = p1; s2a[mf][r] = p2;
    }
  if (l15 == 0){
    #pragma unroll
    for (int mf = 0; mf < 4; ++mf)
      #pragma unroll
      for (int r = 0; r < 4; ++r){
        int row = mf*16 + lg*4 + r;
        part[(row*8 + wid)*2]     = s1a[mf][r];
        part[(row*8 + wid)*2 + 1] = s2a[mf][r];
      }
  }
  __syncthreads();
  if (tid < 64){
    float t1 = 0.f, t2 = 0.f;
    #pragma unroll
    for (int w = 0; w < 8; ++w){
      t1 += part[(tid*8 + w)*2];
      t2 += part[(tid*8 + w)*2 + 1];
    }
    float mu = t1*(1.f/384.f);
    lnf[tid*2]     = mu;
    lnf[tid*2 + 1] = rsqrtf(t2*(1.f/384.f) - mu*mu + 1e-5f);
  }
  __syncthreads();
  #pragma unroll
  for (int mf = 0; mf < 4; ++mf)
    #pragma unroll
    for (int r = 0; r < 4; ++r){
      int row = mf*16 + lg*4 + r;
      float mu = lnf[row*2], rstd = lnf[row*2 + 1];
      #pragma unroll
      for (int t = 0; t < 3; ++t){
        int col = (wid + 8*t)*16 + l15;
        float resid = b2f(*(const u16*)(xb + row*768 + ((col*2) ^ ((row&15)<<4))));
        out[(size_t)(gt0 + row)*DIM + col] =
            resid + (acc2[mf][t][r]-mu)*rstd*n2g[col] + n2b[col];
      }
    }
}

extern "C" void kernel_launch(void* const* d_in, const int* in_sizes, int n_in,
                              void* d_out, int out_size, void* d_ws, size_t ws_size,
                              hipStream_t stream){
  const float* x           = (const float*)d_in[0];
  const float* qkv_w       = (const float*)d_in[1];
  const float* q_bias      = (const float*)d_in[2];
  const float* v_bias      = (const float*)d_in[3];
  const float* logit_scale = (const float*)d_in[4];
  const float* cpb_w1      = (const float*)d_in[5];
  const float* cpb_b1      = (const float*)d_in[6];
  const float* cpb_w2      = (const float*)d_in[7];
  const float* proj_w      = (const float*)d_in[8];
  const float* proj_b      = (const float*)d_in[9];
  const float* n1g         = (const float*)d_in[10];
  const float* n1b         = (const float*)d_in[11];
  const float* n2g         = (const float*)d_in[12];
  const float* n2b         = (const float*)d_in[13];
  const float* mlp_w1      = (const float*)d_in[14];
  const float* mlp_b1      = (const float*)d_in[15];
  const float* mlp_w2      = (const float*)d_in[16];
  const float* mlp_b2      = (const float*)d_in[17];

  // ws: tab 8K | biasfull 116K | outwin 77.07M | qkvbf .88M | pwbf .29M | w1bf 1.18M | w2bf 1.18M
  char* ws = (char*)d_ws;
  float* tab      = (float*)ws;
  float* biasfull = (float*)(ws + 8192);
  u16*  outwin = (u16*)(ws + 126976);
  u16*  qkvbf  = (u16*)(ws + 126976 + 77070336ull);
  u16*  pwbf   = (u16*)(ws + 126976 + 77070336ull + 884736ull);
  u16*  w1bf   = (u16*)(ws + 126976 + 77070336ull + 884736ull + 294912ull);
  u16*  w2bf   = (u16*)(ws + 126976 + 77070336ull + 884736ull + 294912ull + 1179648ull);
  float* x1  = (float*)d_out;
  float* out = (float*)d_out;

  hipLaunchKernelGGL(k_bias, dim3(169), dim3(256), 0, stream, cpb_w1, cpb_b1, cpb_w2, tab);
  hipLaunchKernelGGL(k_bias2, dim3(12), dim3(256), 0, stream, tab, biasfull);
  hipLaunchKernelGGL(k_wconv, dim3(1024), dim3(256), 0, stream,
                     mlp_w1, mlp_w2, qkv_w, proj_w, w1bf, w2bf, qkvbf, pwbf);
  hipLaunchKernelGGL(k_attn, dim3(NWIN), dim3(256), 0, stream,
                     x, qkvbf, q_bias, v_bias, logit_scale, biasfull, outwin);
  hipLaunchKernelGGL(k_proj, dim3(TOKENS/64), dim3(256), 0, stream,
                     outwin, pwbf, proj_b, x, n1g, n1b, x1);
  hipLaunchKernelGGL(k_mlp, dim3(TOKENS/64), dim3(512), 0, stream,
                     x1, w1bf, mlp_b1, w2bf, mlp_b2, n2g, n2b, out);
}

// Round 7
// 1978.027 us; speedup vs baseline: 4.9174x; 1.0268x over previous
//
#include <hip/hip_runtime.h>
#include <hip/hip_bf16.h>
#include <math.h>

#define DIM 384
#define NH 12
#define HD 32
#define NWIN 2048          // B * 64 windows
#define TOKENS 100352      // B * 56 * 56

typedef unsigned short u16;
typedef unsigned int u32;
typedef __attribute__((ext_vector_type(8))) short bf16x8;
typedef __attribute__((ext_vector_type(4))) float f32x4;

__device__ __forceinline__ float b2f(u16 u){ return __uint_as_float(((u32)u) << 16); }
__device__ __forceinline__ u16 f2b(float f){
  u32 x = __float_as_uint(f);
  return (u16)((x + 0x7FFFu + ((x >> 16) & 1u)) >> 16);   // RNE
}

// ---------------- weight pre-convert fp32 -> bf16 ----------------
__global__ void k_wconv(const float* __restrict__ w1, const float* __restrict__ w2,
                        const float* __restrict__ qw, const float* __restrict__ pw,
                        u16* __restrict__ w1bf, u16* __restrict__ w2bf,
                        u16* __restrict__ qwbf, u16* __restrict__ pwbf){
  const int n12 = 1536*384, n3 = 1152*384, n4 = 384*384;
  for (int i = blockIdx.x*blockDim.x + threadIdx.x; i < n12; i += gridDim.x*blockDim.x){
    w1bf[i] = f2b(w1[i]);
    w2bf[i] = f2b(w2[i]);
    if (i < n3) qwbf[i] = f2b(qw[i]);
    if (i < n4) pwbf[i] = f2b(pw[i]);
  }
}

// ---------------- CPB bias table: tab[169][12] ----------------
__global__ void k_bias(const float* __restrict__ w1, const float* __restrict__ b1,
                       const float* __restrict__ w2, float* __restrict__ tab){
  __shared__ float hid[512];
  int e = blockIdx.x;
  int i = e / 13, j = e % 13;
  float t0 = (float)(i - 6) * (8.0f / 6.0f);
  float t1 = (float)(j - 6) * (8.0f / 6.0f);
  t0 = copysignf(log2f(fabsf(t0) + 1.f) * (1.f / 3.f), t0);
  t1 = copysignf(log2f(fabsf(t1) + 1.f) * (1.f / 3.f), t1);
  for (int jj = threadIdx.x; jj < 512; jj += blockDim.x)
    hid[jj] = fmaxf(w1[jj*2]*t0 + w1[jj*2+1]*t1 + b1[jj], 0.f);
  __syncthreads();
  if (threadIdx.x < 12){
    float s = 0.f;
    for (int jj = 0; jj < 512; ++jj) s += hid[jj] * w2[threadIdx.x*512 + jj];
    tab[e*12 + threadIdx.x] = s;
  }
}

// ---------------- expand: biasfull[h][i*49+j] = 16*sigmoid(tab[rpi(i,j)][h]) ----------------
__global__ void k_bias2(const float* __restrict__ tab, float* __restrict__ biasfull){
  int h = blockIdx.x;
  for (int e = threadIdx.x; e < 49*49; e += blockDim.x){
    int i = e / 49, j = e - (e/49)*49;
    int ih = i/7, iw = i - ih*7, jh = j/7, jw = j - jh*7;
    float bv = tab[((ih-jh+6)*13 + (iw-jw+6))*12 + h];
    biasfull[h*2401 + e] = 16.f / (1.f + expf(-bv));
  }
}

// ---------------- fused QKV + cosine attention, one block per window ----------------
// v2: 53248B LDS (3 blocks/CU), 3 barriers/head, B-prefetch double-buffer,
// precomputed mask, early biasfull loads.
__global__ __launch_bounds__(256, 3) void k_attn(
    const float* __restrict__ x, const u16* __restrict__ qkvbf,
    const float* __restrict__ q_bias, const float* __restrict__ v_bias,
    const float* __restrict__ logit_scale, const float* __restrict__ biasfull,
    u16* __restrict__ outwin){
  __shared__ __align__(16) char smem[53248];
  char* xb = smem;                 // [50][768B] bf16 swz ^((row&15)<<4); row 49 = zeros
  char* qn = smem + 38400;         // [64][80B] bf16
  char* kn = smem + 43520;         // [64][80B]
  char* vt = smem + 48640;         // [32][144B] bf16 (V^T)
  char* pb = smem + 38400;         // alias qn+kn after QK^T: [64][144B]

  int tid  = threadIdx.x;
  int lane = tid & 63, wid = tid >> 6;
  int l15  = lane & 15, lg = lane >> 4;
  int win = blockIdx.x;
  int b = win >> 6, wi = win & 63;
  int wh = wi >> 3, ww = wi & 7;

  // stage rolled/windowed x tile (rows 0-48) + zero row 49
  for (int e = tid; e < 50*48; e += 256){
    int r = e / 48, q8 = e - (e/48)*48;
    bf16x8 v = (bf16x8){0,0,0,0,0,0,0,0};
    if (r < 49){
      int th = r / 7, tw = r - th*7;
      int gh = wh*7 + th + 3; if (gh >= 56) gh -= 56;
      int gw = ww*7 + tw + 3; if (gw >= 56) gw -= 56;
      const float4* src = (const float4*)(x + ((size_t)(b*3136 + gh*56 + gw))*DIM + q8*8);
      float4 a = src[0], c = src[1];
      v[0]=(short)f2b(a.x); v[1]=(short)f2b(a.y); v[2]=(short)f2b(a.z); v[3]=(short)f2b(a.w);
      v[4]=(short)f2b(c.x); v[5]=(short)f2b(c.y); v[6]=(short)f2b(c.z); v[7]=(short)f2b(c.w);
    }
    *(bf16x8*)(xb + r*768 + ((q8*16) ^ ((r&15)<<4))) = v;
  }

  // precompute shift-mask + bias-table index (head-independent): [nf][r]
  float mask16[4][4];
  int   bidx[4][4];
  #pragma unroll
  for (int nf = 0; nf < 4; ++nf){
    int j = nf*16 + l15;
    int j2 = j < 49 ? j : 48;
    int jh = j2/7, jw = j2 - jh*7;
    int ghj = wh*7+jh, gwj = ww*7+jw;
    int zj = (ghj<49?0:(ghj<53?1:2))*3 + (gwj<49?0:(gwj<53?1:2));
    #pragma unroll
    for (int r = 0; r < 4; ++r){
      int i = wid*16 + lg*4 + r;
      int i2 = i < 49 ? i : 48;
      int ih = i2/7, iw = i2 - ih*7;
      int ghi = wh*7+ih, gwi = ww*7+iw;
      int zi = (ghi<49?0:(ghi<53?1:2))*3 + (gwi<49?0:(gwi<53?1:2));
      mask16[nf][r] = (j < 49) ? (zi != zj ? -100.f : 0.f) : -1e30f;
      bidx[nf][r]   = i2*49 + j2;
    }
  }
  __syncthreads();

  int arow = wid*16 + l15;
  int arc  = arow < 49 ? arow : 49;            // clamped A-row (49 = zero row)

  for (int h = 0; h < NH; ++h){
    // early loads: rel-pos bias (used post-QK^T) + scalars
    float bias16[4][4];
    #pragma unroll
    for (int nf = 0; nf < 4; ++nf)
      #pragma unroll
      for (int r = 0; r < 4; ++r)
        bias16[nf][r] = biasfull[h*2401 + bidx[nf][r]];
    float qb0 = q_bias[h*HD + l15], qb1 = q_bias[h*HD + 16 + l15];
    float vb0 = v_bias[h*HD + l15], vb1 = v_bias[h*HD + 16 + l15];
    float sc = __expf(fminf(logit_scale[h], 4.6051702f));

    // ---- QKV GEMM with double-buffered B prefetch ----
    f32x4 acc[6];
    #pragma unroll
    for (int nf = 0; nf < 6; ++nf) acc[nf] = (f32x4){0.f,0.f,0.f,0.f};
    const u16* bp[6];
    #pragma unroll
    for (int nf = 0; nf < 6; ++nf){
      int n = nf*16 + l15;
      int m = n >> 5, c = n & 31;
      bp[nf] = qkvbf + (size_t)(m*DIM + h*HD + c)*DIM;
    }
    bf16x8 bA[6], bB[6];
    #pragma unroll
    for (int nf = 0; nf < 6; ++nf) bA[nf] = *(const bf16x8*)(bp[nf] + lg*8);
    #pragma unroll
    for (int ks2 = 0; ks2 < 12; ks2 += 2){
      // even: compute bA, prefetch bB (ks2+1)
      #pragma unroll
      for (int nf = 0; nf < 6; ++nf) bB[nf] = *(const bf16x8*)(bp[nf] + (ks2+1)*32 + lg*8);
      {
        int k0 = ks2*32 + lg*8;
        bf16x8 af = *(const bf16x8*)(xb + arc*768 + ((k0*2) ^ ((arc&15)<<4)));
        #pragma unroll
        for (int nf = 0; nf < 6; ++nf)
          acc[nf] = __builtin_amdgcn_mfma_f32_16x16x32_bf16(af, bA[nf], acc[nf], 0, 0, 0);
      }
      // odd: compute bB, prefetch bA (ks2+2)
      if (ks2 + 2 < 12){
        #pragma unroll
        for (int nf = 0; nf < 6; ++nf) bA[nf] = *(const bf16x8*)(bp[nf] + (ks2+2)*32 + lg*8);
      }
      {
        int k0 = (ks2+1)*32 + lg*8;
        bf16x8 af = *(const bf16x8*)(xb + arc*768 + ((k0*2) ^ ((arc&15)<<4)));
        #pragma unroll
        for (int nf = 0; nf < 6; ++nf)
          acc[nf] = __builtin_amdgcn_mfma_f32_16x16x32_bf16(af, bB[nf], acc[nf], 0, 0, 0);
      }
    }
    // ---- bias + cosine norm ----
    #pragma unroll
    for (int r = 0; r < 4; ++r){
      acc[0][r] += qb0; acc[1][r] += qb1;
      acc[4][r] += vb0; acc[5][r] += vb1;
      float sq = acc[0][r]*acc[0][r] + acc[1][r]*acc[1][r];
      float sk = acc[2][r]*acc[2][r] + acc[3][r]*acc[3][r];
      #pragma unroll
      for (int off = 1; off < 16; off <<= 1){
        sq += __shfl_xor(sq, off, 64);
        sk += __shfl_xor(sk, off, 64);
      }
      float rq = sc / fmaxf(sqrtf(sq), 1e-12f);
      float rk = 1.f / fmaxf(sqrtf(sk), 1e-12f);
      acc[0][r] *= rq; acc[1][r] *= rq;
      acc[2][r] *= rk; acc[3][r] *= rk;
    }
    // ---- write qn/kn (stride 80B) + vt transposed (stride 144B) ----
    #pragma unroll
    for (int r = 0; r < 4; ++r){
      int row = wid*16 + lg*4 + r;
      *(u16*)(qn + row*80 + l15*2)      = f2b(acc[0][r]);
      *(u16*)(qn + row*80 + 32 + l15*2) = f2b(acc[1][r]);
      *(u16*)(kn + row*80 + l15*2)      = f2b(acc[2][r]);
      *(u16*)(kn + row*80 + 32 + l15*2) = f2b(acc[3][r]);
      *(u16*)(vt + l15*144 + row*2)        = f2b(acc[4][r]);
      *(u16*)(vt + (16+l15)*144 + row*2)   = f2b(acc[5][r]);
    }
    __syncthreads();                           // A: qn/kn/vt visible
    // ---- QK^T ----
    f32x4 s[4];
    {
      bf16x8 qa = *(const bf16x8*)(qn + arow*80 + lg*16);   // own-wave rows, 0..63 all written
      #pragma unroll
      for (int nf = 0; nf < 4; ++nf){
        int bcol = nf*16 + l15;
        bf16x8 kb = *(const bf16x8*)(kn + bcol*80 + lg*16);
        s[nf] = __builtin_amdgcn_mfma_f32_16x16x32_bf16(qa, kb,
                  (f32x4){0.f,0.f,0.f,0.f}, 0, 0, 0);
      }
    }
    __syncthreads();                           // B: qn/kn reads done -> pb writable
    // ---- bias + mask + softmax ----
    #pragma unroll
    for (int nf = 0; nf < 4; ++nf)
      #pragma unroll
      for (int r = 0; r < 4; ++r)
        s[nf][r] += bias16[nf][r] + mask16[nf][r];
    #pragma unroll
    for (int r = 0; r < 4; ++r){
      float m = fmaxf(fmaxf(s[0][r], s[1][r]), fmaxf(s[2][r], s[3][r]));
      #pragma unroll
      for (int off = 1; off < 16; off <<= 1) m = fmaxf(m, __shfl_xor(m, off, 64));
      float e0 = __expf(s[0][r]-m), e1 = __expf(s[1][r]-m);
      float e2 = __expf(s[2][r]-m), e3 = __expf(s[3][r]-m);
      float sum = e0+e1+e2+e3;
      #pragma unroll
      for (int off = 1; off < 16; off <<= 1) sum += __shfl_xor(sum, off, 64);
      float rs = 1.f/sum;
      s[0][r] = e0*rs; s[1][r] = e1*rs; s[2][r] = e2*rs; s[3][r] = e3*rs;
    }
    // ---- write P (wave-local rows; no barrier needed before PV) ----
    #pragma unroll
    for (int nf = 0; nf < 4; ++nf){
      int j = nf*16 + l15;
      #pragma unroll
      for (int r = 0; r < 4; ++r){
        int i = wid*16 + lg*4 + r;
        *(u16*)(pb + i*144 + j*2) = f2b(s[nf][r]);
      }
    }
    // ---- PV: A = own wave's P rows (wave-local), B = vt (barrier-A protected) ----
    f32x4 o[2];
    o[0] = (f32x4){0.f,0.f,0.f,0.f}; o[1] = o[0];
    #pragma unroll
    for (int ksp = 0; ksp < 2; ++ksp){
      int k0 = ksp*32 + lg*8;
      int prow = wid*16 + l15;
      bf16x8 pa = *(const bf16x8*)(pb + prow*144 + k0*2);
      #pragma unroll
      for (int nf = 0; nf < 2; ++nf){
        bf16x8 vb = *(const bf16x8*)(vt + (nf*16+l15)*144 + k0*2);
        o[nf] = __builtin_amdgcn_mfma_f32_16x16x32_bf16(pa, vb, o[nf], 0, 0, 0);
      }
    }
    #pragma unroll
    for (int r = 0; r < 4; ++r){
      int row = wid*16 + lg*4 + r;
      if (row < 49){
        size_t base = ((size_t)win*49 + row)*DIM + h*HD;
        outwin[base + l15]      = f2b(o[0][r]);
        outwin[base + 16 + l15] = f2b(o[1][r]);
      }
    }
    __syncthreads();                           // D: pb/vt reads done before next head
  }
}

// ---------------- proj + window-reverse + LN1 + residual -> x1 (d_out), MFMA ----------------
__global__ __launch_bounds__(256) void k_proj(
    const u16* __restrict__ outwin, const u16* __restrict__ pwbf,
    const float* __restrict__ proj_b, const float* __restrict__ x,
    const float* __restrict__ n1g, const float* __restrict__ n1b,
    float* __restrict__ x1){
  __shared__ __align__(16) char sb[49152];     // 64x384 bf16 swizzled
  int tid  = threadIdx.x;
  int lane = tid & 63, wid = tid >> 6;
  int l15  = lane & 15, lg = lane >> 4;
  int gt0 = blockIdx.x * 64;

  for (int e = tid; e < 64*48; e += 256){      // gather (window-reverse) 64 token rows
    int r = e / 48, q8 = e - (e/48)*48;
    int gtok = gt0 + r;
    int b = gtok / 3136, r2 = gtok - b*3136;
    int oh = r2 / 56, ow = r2 - oh*56;
    int hs = oh + 53; if (hs >= 56) hs -= 56;
    int ws2 = ow + 53; if (ws2 >= 56) ws2 -= 56;
    int win = b*64 + (hs/7)*8 + (ws2/7);
    int row = (hs%7)*7 + (ws2%7);
    bf16x8 v = *(const bf16x8*)(outwin + ((size_t)win*49 + row)*DIM + q8*8);
    *(bf16x8*)(sb + r*768 + ((q8*16) ^ ((r&7)<<4))) = v;
  }
  f32x4 acc[24];
  #pragma unroll
  for (int nf = 0; nf < 24; ++nf){
    float pbv = proj_b[nf*16 + l15];
    acc[nf] = (f32x4){pbv, pbv, pbv, pbv};
  }
  __syncthreads();
  #pragma unroll 2
  for (int ksp = 0; ksp < 12; ++ksp){
    int k0 = ksp*32 + lg*8;
    int arow = wid*16 + l15;
    bf16x8 af = *(const bf16x8*)(sb + arow*768 + ((k0*2) ^ ((arow&7)<<4)));
    #pragma unroll
    for (int nf = 0; nf < 24; ++nf){
      bf16x8 bf = *(const bf16x8*)(pwbf + (size_t)(nf*16+l15)*DIM + k0);
      acc[nf] = __builtin_amdgcn_mfma_f32_16x16x32_bf16(af, bf, acc[nf], 0, 0, 0);
    }
  }
  // ---- LN1 + residual epilogue ----
  float s1[4] = {0.f,0.f,0.f,0.f}, s2[4] = {0.f,0.f,0.f,0.f};
  #pragma unroll
  for (int nf = 0; nf < 24; ++nf)
    #pragma unroll
    for (int r = 0; r < 4; ++r){
      float v = acc[nf][r];
      s1[r] += v; s2[r] += v*v;
    }
  #pragma unroll
  for (int r = 0; r < 4; ++r){
    #pragma unroll
    for (int off = 1; off < 16; off <<= 1){
      s1[r] += __shfl_xor(s1[r], off, 64);
      s2[r] += __shfl_xor(s2[r], off, 64);
    }
  }
  #pragma unroll
  for (int r = 0; r < 4; ++r){
    float mu = s1[r]*(1.f/384.f);
    float rstd = rsqrtf(s2[r]*(1.f/384.f) - mu*mu + 1e-5f);
    int grow = gt0 + wid*16 + lg*4 + r;
    #pragma unroll
    for (int nf = 0; nf < 24; ++nf){
      int col = nf*16 + l15;
      x1[(size_t)grow*DIM + col] =
          (acc[nf][r]-mu)*rstd*n1g[col] + n1b[col] + x[(size_t)grow*DIM + col];
    }
  }
}

// ---------------- fused MLP v3: 512 thr / 8 waves, 64 tokens/block ----------------
__global__ __launch_bounds__(512, 4) void k_mlp(
    const float* __restrict__ x1, const u16* __restrict__ w1bf, const float* __restrict__ b1,
    const u16* __restrict__ w2bf, const float* __restrict__ b2,
    const float* __restrict__ n2g, const float* __restrict__ n2b,
    float* __restrict__ out){
  __shared__ __align__(16) char smem[65536];
  char* xb = smem;                 // [64][768B] bf16, swz ^((row&15)<<4)
  char* hb = smem + 49152;         // [64][256B] bf16, swz ^((row&15)<<4)

  int tid  = threadIdx.x;
  int lane = tid & 63, wid = tid >> 6;        // 8 waves
  int l15  = lane & 15, lg = lane >> 4;
  int wm = wid >> 2, wn = wid & 3;            // GEMM1 grid 2m x 4n
  int gt0 = blockIdx.x * 64;

  for (int e = tid; e < 64*48; e += 512){
    int r = e / 48, q8 = e - (e/48)*48;
    const float4* src = (const float4*)(x1 + (size_t)(gt0+r)*DIM + q8*8);
    float4 a = src[0], c = src[1];
    bf16x8 v;
    v[0]=(short)f2b(a.x); v[1]=(short)f2b(a.y); v[2]=(short)f2b(a.z); v[3]=(short)f2b(a.w);
    v[4]=(short)f2b(c.x); v[5]=(short)f2b(c.y); v[6]=(short)f2b(c.z); v[7]=(short)f2b(c.w);
    *(bf16x8*)(xb + r*768 + ((q8*16) ^ ((r&15)<<4))) = v;
  }

  f32x4 acc2[4][3];
  #pragma unroll
  for (int mf = 0; mf < 4; ++mf)
    #pragma unroll
    for (int t = 0; t < 3; ++t){
      float bb = b2[(wid + 8*t)*16 + l15];
      acc2[mf][t] = (f32x4){bb, bb, bb, bb};
    }
  __syncthreads();                             // xb ready

  for (int hc = 0; hc < 1536; hc += 128){
    f32x4 accH[2][2];
    #pragma unroll
    for (int mf = 0; mf < 2; ++mf)
      #pragma unroll
      for (int nh = 0; nh < 2; ++nh){
        float bb = b1[hc + wn*32 + nh*16 + l15];
        accH[mf][nh] = (f32x4){bb, bb, bb, bb};
      }
    #pragma unroll 2
    for (int ksp = 0; ksp < 12; ++ksp){
      int k0 = ksp*32 + lg*8;
      bf16x8 afr[2], bfr[2];
      #pragma unroll
      for (int mf = 0; mf < 2; ++mf){
        int row = wm*32 + mf*16 + l15;
        afr[mf] = *(const bf16x8*)(xb + row*768 + ((k0*2) ^ ((row&15)<<4)));
      }
      #pragma unroll
      for (int nh = 0; nh < 2; ++nh)
        bfr[nh] = *(const bf16x8*)(w1bf + (size_t)(hc + wn*32 + nh*16 + l15)*384 + k0);
      #pragma unroll
      for (int mf = 0; mf < 2; ++mf)
        #pragma unroll
        for (int nh = 0; nh < 2; ++nh)
          accH[mf][nh] = __builtin_amdgcn_mfma_f32_16x16x32_bf16(afr[mf], bfr[nh], accH[mf][nh], 0, 0, 0);
    }
    #pragma unroll
    for (int mf = 0; mf < 2; ++mf)
      #pragma unroll
      for (int nh = 0; nh < 2; ++nh)
        #pragma unroll
        for (int r = 0; r < 4; ++r){
          float v = accH[mf][nh][r];
          v = 0.5f*v*(1.f + erff(v*0.70710678f));
          int row = wm*32 + mf*16 + lg*4 + r;
          int col = wn*32 + nh*16 + l15;
          *(u16*)(hb + row*256 + ((col*2) ^ ((row&15)<<4))) = f2b(v);
        }
    __syncthreads();                           // hb visible
    #pragma unroll
    for (int ks = 0; ks < 4; ++ks){
      int k0 = ks*32 + lg*8;
      bf16x8 pa[4];
      #pragma unroll
      for (int mf = 0; mf < 4; ++mf){
        int row = mf*16 + l15;
        pa[mf] = *(const bf16x8*)(hb + row*256 + ((k0*2) ^ ((row&15)<<4)));
      }
      #pragma unroll
      for (int t = 0; t < 3; ++t){
        bf16x8 pbt = *(const bf16x8*)(w2bf + (size_t)((wid + 8*t)*16 + l15)*1536 + hc + k0);
        #pragma unroll
        for (int mf = 0; mf < 4; ++mf)
          acc2[mf][t] = __builtin_amdgcn_mfma_f32_16x16x32_bf16(pa[mf], pbt, acc2[mf][t], 0, 0, 0);
      }
    }
    __syncthreads();                           // hb reads done before next GELU overwrite
  }

  // ---- LN2 (cross-wave via LDS) + residual epilogue ----
  float* part = (float*)hb;                    // [64][8][2] f32 (hb dead)
  float* lnf  = (float*)(hb + 4096);           // [64][2]
  float s1a[4][4], s2a[4][4];
  #pragma unroll
  for (int mf = 0; mf < 4; ++mf)
    #pragma unroll
    for (int r = 0; r < 4; ++r){
      float p1 = acc2[mf][0][r] + acc2[mf][1][r] + acc2[mf][2][r];
      float p2 = acc2[mf][0][r]*acc2[mf][0][r] + acc2[mf][1][r]*acc2[mf][1][r]
               + acc2[mf][2][r]*acc2[mf][2][r];
      #pragma unroll
      for (int off = 1; off < 16; off <<= 1){
        p1 += __shfl_xor(p1, off, 64);
        p2 += __shfl_xor(p2, off, 64);
      }
      s1a[mf][r] = p1; s2a[mf][r] = p2;
    }
  if (l15 == 0){
    #pragma unroll
    for (int mf = 0; mf < 4; ++mf)
      #pragma unroll
      for (int r = 0; r < 4; ++r){
        int row = mf*16 + lg*4 + r;
        part[(row*8 + wid)*2]     = s1a[mf][r];
        part[(row*8 + wid)*2 + 1] = s2a[mf][r];
      }
  }
  __syncthreads();
  if (tid < 64){
    float t1 = 0.f, t2 = 0.f;
    #pragma unroll
    for (int w = 0; w < 8; ++w){
      t1 += part[(tid*8 + w)*2];
      t2 += part[(tid*8 + w)*2 + 1];
    }
    float mu = t1*(1.f/384.f);
    lnf[tid*2]     = mu;
    lnf[tid*2 + 1] = rsqrtf(t2*(1.f/384.f) - mu*mu + 1e-5f);
  }
  __syncthreads();
  #pragma unroll
  for (int mf = 0; mf < 4; ++mf)
    #pragma unroll
    for (int r = 0; r < 4; ++r){
      int row = mf*16 + lg*4 + r;
      float mu = lnf[row*2], rstd = lnf[row*2 + 1];
      #pragma unroll
      for (int t = 0; t < 3; ++t){
        int col = (wid + 8*t)*16 + l15;
        float resid = b2f(*(const u16*)(xb + row*768 + ((col*2) ^ ((row&15)<<4))));
        out[(size_t)(gt0 + row)*DIM + col] =
            resid + (acc2[mf][t][r]-mu)*rstd*n2g[col] + n2b[col];
      }
    }
}

extern "C" void kernel_launch(void* const* d_in, const int* in_sizes, int n_in,
                              void* d_out, int out_size, void* d_ws, size_t ws_size,
                              hipStream_t stream){
  const float* x           = (const float*)d_in[0];
  const float* qkv_w       = (const float*)d_in[1];
  const float* q_bias      = (const float*)d_in[2];
  const float* v_bias      = (const float*)d_in[3];
  const float* logit_scale = (const float*)d_in[4];
  const float* cpb_w1      = (const float*)d_in[5];
  const float* cpb_b1      = (const float*)d_in[6];
  const float* cpb_w2      = (const float*)d_in[7];
  const float* proj_w      = (const float*)d_in[8];
  const float* proj_b      = (const float*)d_in[9];
  const float* n1g         = (const float*)d_in[10];
  const float* n1b         = (const float*)d_in[11];
  const float* n2g         = (const float*)d_in[12];
  const float* n2b         = (const float*)d_in[13];
  const float* mlp_w1      = (const float*)d_in[14];
  const float* mlp_b1      = (const float*)d_in[15];
  const float* mlp_w2      = (const float*)d_in[16];
  const float* mlp_b2      = (const float*)d_in[17];

  // ws: tab 8K | biasfull 116K | outwin 77.07M | qkvbf .88M | pwbf .29M | w1bf 1.18M | w2bf 1.18M
  char* ws = (char*)d_ws;
  float* tab      = (float*)ws;
  float* biasfull = (float*)(ws + 8192);
  u16*  outwin = (u16*)(ws + 126976);
  u16*  qkvbf  = (u16*)(ws + 126976 + 77070336ull);
  u16*  pwbf   = (u16*)(ws + 126976 + 77070336ull + 884736ull);
  u16*  w1bf   = (u16*)(ws + 126976 + 77070336ull + 884736ull + 294912ull);
  u16*  w2bf   = (u16*)(ws + 126976 + 77070336ull + 884736ull + 294912ull + 1179648ull);
  float* x1  = (float*)d_out;
  float* out = (float*)d_out;

  hipLaunchKernelGGL(k_bias, dim3(169), dim3(256), 0, stream, cpb_w1, cpb_b1, cpb_w2, tab);
  hipLaunchKernelGGL(k_bias2, dim3(12), dim3(256), 0, stream, tab, biasfull);
  hipLaunchKernelGGL(k_wconv, dim3(1024), dim3(256), 0, stream,
                     mlp_w1, mlp_w2, qkv_w, proj_w, w1bf, w2bf, qkvbf, pwbf);
  hipLaunchKernelGGL(k_attn, dim3(NWIN), dim3(256), 0, stream,
                     x, qkvbf, q_bias, v_bias, logit_scale, biasfull, outwin);
  hipLaunchKernelGGL(k_proj, dim3(TOKENS/64), dim3(256), 0, stream,
                     outwin, pwbf, proj_b, x, n1g, n1b, x1);
  hipLaunchKernelGGL(k_mlp, dim3(TOKENS/64), dim3(512), 0, stream,
                     x1, w1bf, mlp_b1, w2bf, mlp_b2, n2g, n2b, out);
}

// Round 8
// 1558.221 us; speedup vs baseline: 6.2422x; 1.2694x over previous
//
#include <hip/hip_runtime.h>
#include <hip/hip_bf16.h>
#include <math.h>

#define DIM 384
#define NH 12
#define HD 32
#define NWIN 2048          // B * 64 windows
#define TOKENS 100352      // B * 56 * 56

typedef unsigned short u16;
typedef unsigned int u32;
typedef __attribute__((ext_vector_type(8))) short bf16x8;
typedef __attribute__((ext_vector_type(4))) float f32x4;

__device__ __forceinline__ float b2f(u16 u){ return __uint_as_float(((u32)u) << 16); }
__device__ __forceinline__ u16 f2b(float f){
  u32 x = __float_as_uint(f);
  return (u16)((x + 0x7FFFu + ((x >> 16) & 1u)) >> 16);   // RNE
}

// ---------------- weight pre-convert fp32 -> bf16 ----------------
__global__ void k_wconv(const float* __restrict__ w1, const float* __restrict__ w2,
                        const float* __restrict__ qw, const float* __restrict__ pw,
                        u16* __restrict__ w1bf, u16* __restrict__ w2bf,
                        u16* __restrict__ qwbf, u16* __restrict__ pwbf){
  const int n12 = 1536*384, n3 = 1152*384, n4 = 384*384;
  for (int i = blockIdx.x*blockDim.x + threadIdx.x; i < n12; i += gridDim.x*blockDim.x){
    w1bf[i] = f2b(w1[i]);
    w2bf[i] = f2b(w2[i]);
    if (i < n3) qwbf[i] = f2b(qw[i]);
    if (i < n4) pwbf[i] = f2b(pw[i]);
  }
}

// ---------------- CPB bias table: tab[169][12] ----------------
__global__ void k_bias(const float* __restrict__ w1, const float* __restrict__ b1,
                       const float* __restrict__ w2, float* __restrict__ tab){
  __shared__ float hid[512];
  int e = blockIdx.x;
  int i = e / 13, j = e % 13;
  float t0 = (float)(i - 6) * (8.0f / 6.0f);
  float t1 = (float)(j - 6) * (8.0f / 6.0f);
  t0 = copysignf(log2f(fabsf(t0) + 1.f) * (1.f / 3.f), t0);
  t1 = copysignf(log2f(fabsf(t1) + 1.f) * (1.f / 3.f), t1);
  for (int jj = threadIdx.x; jj < 512; jj += blockDim.x)
    hid[jj] = fmaxf(w1[jj*2]*t0 + w1[jj*2+1]*t1 + b1[jj], 0.f);
  __syncthreads();
  if (threadIdx.x < 12){
    float s = 0.f;
    for (int jj = 0; jj < 512; ++jj) s += hid[jj] * w2[threadIdx.x*512 + jj];
    tab[e*12 + threadIdx.x] = s;
  }
}

// ---------------- expand: biasfull[h][i*49+j] = 16*sigmoid(tab[rpi(i,j)][h]) ----------------
__global__ void k_bias2(const float* __restrict__ tab, float* __restrict__ biasfull){
  int h = blockIdx.x;
  for (int e = threadIdx.x; e < 49*49; e += blockDim.x){
    int i = e / 49, j = e - (e/49)*49;
    int ih = i/7, iw = i - ih*7, jh = j/7, jw = j - jh*7;
    float bv = tab[((ih-jh+6)*13 + (iw-jw+6))*12 + h];
    biasfull[h*2401 + e] = 16.f / (1.f + expf(-bv));
  }
}

// ---------------- k_qkv: windowed QKV GEMM, LDS double-buffered ----------------
// grid (2048 windows, 3 tiles: 0=q 1=k 2=v), 512 thr / 8 waves (2m x 4n).
// Writes Q (ws, cosine-normed * scale), K (d_out, normed), V (d_out+77MB, +bias),
// all bf16 [win][h][49][32].
__device__ __forceinline__ void qkv_stage(
    int kc, char* Ad, char* Bd, const float* __restrict__ x, size_t asrc,
    bool arok, int ar, int aq, const u16* __restrict__ bbase, int tid){
  if (arok){
    float4 v4 = *(const float4*)(x + asrc + kc + aq*4);
    u16 p0=f2b(v4.x), p1=f2b(v4.y), p2=f2b(v4.z), p3=f2b(v4.w);
    *(uint2*)(Ad + ar*80 + aq*8) = (uint2){(u32)p0|((u32)p1<<16), (u32)p2|((u32)p3<<16)};
  } else {
    *(uint2*)(Ad + ar*80 + aq*8) = (uint2){0u, 0u};
  }
  #pragma unroll
  for (int i = 0; i < 3; ++i){
    int s = tid + i*512, n = s >> 2, g = s & 3;
    bf16x8 v = *(const bf16x8*)(bbase + (size_t)n*DIM + kc + (g ^ (n&3))*8);
    *(bf16x8*)(Bd + n*64 + g*16) = v;
  }
}

__global__ __launch_bounds__(512, 4) void k_qkv(
    const float* __restrict__ x, const u16* __restrict__ qkvbf,
    const float* __restrict__ q_bias, const float* __restrict__ v_bias,
    const float* __restrict__ logit_scale,
    u16* __restrict__ Qg, u16* __restrict__ Kg, u16* __restrict__ Vg){
  __shared__ __align__(16) char Ab[2][5120];    // [64][80B] bf16 (40-elem rows)
  __shared__ __align__(16) char Bb[2][24576];   // [384][64B] bf16, granule-swz

  int tid = threadIdx.x;
  int lane = tid & 63, wid = tid >> 6;
  int l15 = lane & 15, lg = lane >> 4;
  int wm = wid >> 2, wn = wid & 3;
  int win = blockIdx.x, NT = blockIdx.y;
  int b = win >> 6, wi = win & 63, wh = wi >> 3, ww = wi & 7;

  int ar = tid >> 3, aq = tid & 7;              // A-stage: row, float4-slot
  bool arok = ar < 49;
  size_t asrc = 0;
  if (arok){
    int th = ar / 7, tw = ar - (ar/7)*7;
    int gh = wh*7 + th + 3; if (gh >= 56) gh -= 56;
    int gw = ww*7 + tw + 3; if (gw >= 56) gw -= 56;
    asrc = ((size_t)(b*3136 + gh*56 + gw))*DIM;
  }
  const u16* bbase = qkvbf + (size_t)NT*384*DIM;

  f32x4 acc[2][6];
  #pragma unroll
  for (int mf = 0; mf < 2; ++mf)
    #pragma unroll
    for (int nf = 0; nf < 6; ++nf) acc[mf][nf] = (f32x4){0.f,0.f,0.f,0.f};

  qkv_stage(0, Ab[0], Bb[0], x, asrc, arok, ar, aq, bbase, tid);
  __syncthreads();

  for (int t = 0; t < 12; ++t){
    int cur = t & 1;
    if (t < 11)
      qkv_stage((t+1)*32, Ab[cur^1], Bb[cur^1], x, asrc, arok, ar, aq, bbase, tid);
    bf16x8 af[2];
    #pragma unroll
    for (int mf = 0; mf < 2; ++mf){
      int row = wm*32 + mf*16 + l15;
      af[mf] = *(const bf16x8*)(Ab[cur] + row*80 + lg*16);
    }
    #pragma unroll
    for (int nf = 0; nf < 6; ++nf){
      int n = wn*96 + nf*16 + l15;
      bf16x8 bfv = *(const bf16x8*)(Bb[cur] + n*64 + ((lg ^ (n&3))*16));
      #pragma unroll
      for (int mf = 0; mf < 2; ++mf)
        acc[mf][nf] = __builtin_amdgcn_mfma_f32_16x16x32_bf16(af[mf], bfv, acc[mf][nf], 0, 0, 0);
    }
    __syncthreads();
  }

  // epilogue: per-head-pair p (head h = wn*3+p, nf pair {2p,2p+1})
  if (NT == 0){        // Q: +bias, cosine norm, * exp(min(logit_scale,ln100))
    #pragma unroll
    for (int p = 0; p < 3; ++p){
      int h = wn*3 + p;
      float qb0 = q_bias[h*32 + l15], qb1 = q_bias[h*32 + 16 + l15];
      float sc = __expf(fminf(logit_scale[h], 4.6051702f));
      #pragma unroll
      for (int mf = 0; mf < 2; ++mf)
        #pragma unroll
        for (int r = 0; r < 4; ++r){
          float a0 = acc[mf][2*p][r] + qb0;
          float a1 = acc[mf][2*p+1][r] + qb1;
          float sq = a0*a0 + a1*a1;
          #pragma unroll
          for (int off = 1; off < 16; off <<= 1) sq += __shfl_xor(sq, off, 64);
          float rq = sc / fmaxf(sqrtf(sq), 1e-12f);
          int grow = wm*32 + mf*16 + lg*4 + r;
          if (grow < 49){
            u16* dst = Qg + (size_t)win*18816 + h*1568 + grow*32;
            dst[l15]      = f2b(a0*rq);
            dst[16 + l15] = f2b(a1*rq);
          }
        }
    }
  } else if (NT == 1){ // K: cosine norm only
    #pragma unroll
    for (int p = 0; p < 3; ++p){
      int h = wn*3 + p;
      #pragma unroll
      for (int mf = 0; mf < 2; ++mf)
        #pragma unroll
        for (int r = 0; r < 4; ++r){
          float a0 = acc[mf][2*p][r], a1 = acc[mf][2*p+1][r];
          float sk = a0*a0 + a1*a1;
          #pragma unroll
          for (int off = 1; off < 16; off <<= 1) sk += __shfl_xor(sk, off, 64);
          float rk = 1.f / fmaxf(sqrtf(sk), 1e-12f);
          int grow = wm*32 + mf*16 + lg*4 + r;
          if (grow < 49){
            u16* dst = Kg + (size_t)win*18816 + h*1568 + grow*32;
            dst[l15]      = f2b(a0*rk);
            dst[16 + l15] = f2b(a1*rk);
          }
        }
    }
  } else {             // V: +bias
    #pragma unroll
    for (int nf = 0; nf < 6; ++nf){
      int col = wn*96 + nf*16 + l15;
      int h = col >> 5, c = col & 31;
      float vb = v_bias[col];
      #pragma unroll
      for (int mf = 0; mf < 2; ++mf){
        int gbase = wm*32 + mf*16 + lg*4;
        u16* dst = Vg + (size_t)win*18816 + h*1568 + c;
        #pragma unroll
        for (int r = 0; r < 4; ++r){
          int grow = gbase + r;
          if (grow < 49) dst[grow*32] = f2b(acc[mf][nf][r] + vb);
        }
      }
    }
  }
}

// ---------------- k_attn2: per-window attention (Q/K/V precomputed) ----------------
// 4 waves, head-loop fully unrolled; one barrier (Q-preload vs outwin alias).
// outwin aliases Qg exactly (both [win][18816 u16]); K/V live in d_out.
__global__ __launch_bounds__(256, 3) void k_attn2(
    const u16* __restrict__ Qg, const u16* __restrict__ Kg, const u16* __restrict__ Vg,
    const float* __restrict__ biasfull, u16* __restrict__ outwin){
  __shared__ __align__(16) char pb[4][2304];    // per-wave P [16][144B]

  int tid = threadIdx.x, lane = tid & 63, wid = tid >> 6;
  int l15 = lane & 15, lg = lane >> 4;
  int win = blockIdx.x;
  int wi = win & 63, wh = wi >> 3, ww = wi & 7;

  // shift-mask + bias-index precompute (rows i = wid*16+lg*4+r, cols j = nf*16+l15)
  float mask16[4][4];
  int   bidx[4][4];
  #pragma unroll
  for (int nf = 0; nf < 4; ++nf){
    int j = nf*16 + l15;
    int j2 = j < 49 ? j : 48;
    int jh = j2/7, jw = j2 - jh*7;
    int ghj = wh*7+jh, gwj = ww*7+jw;
    int zj = (ghj<49?0:(ghj<53?1:2))*3 + (gwj<49?0:(gwj<53?1:2));
    #pragma unroll
    for (int r = 0; r < 4; ++r){
      int i = wid*16 + lg*4 + r;
      int i2 = i < 49 ? i : 48;
      int ih = i2/7, iw = i2 - ih*7;
      int ghi = wh*7+ih, gwi = ww*7+iw;
      int zi = (ghi<49?0:(ghi<53?1:2))*3 + (gwi<49?0:(gwi<53?1:2));
      mask16[nf][r] = (j < 49) ? (zi != zj ? -100.f : 0.f) : -1e30f;
      bidx[nf][r]   = i2*49 + j2;
    }
  }

  const u16* qwin = Qg + (size_t)win*18816;
  const u16* kwin = Kg + (size_t)win*18816;
  const u16* vwin = Vg + (size_t)win*18816;
  char* pbw = pb[wid];

  int arow = wid*16 + l15;
  int arc  = arow < 49 ? arow : 48;

  bf16x8 qa[12];
  #pragma unroll
  for (int h = 0; h < 12; ++h)
    qa[h] = *(const bf16x8*)(qwin + h*1568 + arc*32 + lg*8);
  __syncthreads();                              // all Q reads done before outwin writes

  #pragma unroll
  for (int h = 0; h < 12; ++h){
    // K fragments (clamped j -> no OOB; j>=49 masked later)
    bf16x8 kb[4];
    #pragma unroll
    for (int nf = 0; nf < 4; ++nf){
      int j = nf*16 + l15; int j2 = j < 49 ? j : 48;
      kb[nf] = *(const bf16x8*)(kwin + h*1568 + j2*32 + lg*8);
    }
    // V B-fragments via 8 scalar loads each (V stored row-major [j][c]); P=0 covers j>=49
    bf16x8 vb0[2], vb1[2];
    #pragma unroll
    for (int ksp = 0; ksp < 2; ++ksp){
      #pragma unroll
      for (int tt = 0; tt < 8; ++tt){
        int j = ksp*32 + lg*8 + tt; int j2 = j < 49 ? j : 48;
        vb0[ksp][tt] = (short)vwin[h*1568 + j2*32 + l15];
        vb1[ksp][tt] = (short)vwin[h*1568 + j2*32 + 16 + l15];
      }
    }
    float bias16[4][4];
    #pragma unroll
    for (int nf = 0; nf < 4; ++nf)
      #pragma unroll
      for (int r = 0; r < 4; ++r)
        bias16[nf][r] = biasfull[h*2401 + bidx[nf][r]];
    // QK^T
    f32x4 s[4];
    #pragma unroll
    for (int nf = 0; nf < 4; ++nf)
      s[nf] = __builtin_amdgcn_mfma_f32_16x16x32_bf16(qa[h], kb[nf],
                (f32x4){0.f,0.f,0.f,0.f}, 0, 0, 0);
    // bias + mask + softmax
    #pragma unroll
    for (int nf = 0; nf < 4; ++nf)
      #pragma unroll
      for (int r = 0; r < 4; ++r)
        s[nf][r] += bias16[nf][r] + mask16[nf][r];
    #pragma unroll
    for (int r = 0; r < 4; ++r){
      float m = fmaxf(fmaxf(s[0][r], s[1][r]), fmaxf(s[2][r], s[3][r]));
      #pragma unroll
      for (int off = 1; off < 16; off <<= 1) m = fmaxf(m, __shfl_xor(m, off, 64));
      float e0 = __expf(s[0][r]-m), e1 = __expf(s[1][r]-m);
      float e2 = __expf(s[2][r]-m), e3 = __expf(s[3][r]-m);
      float sum = e0+e1+e2+e3;
      #pragma unroll
      for (int off = 1; off < 16; off <<= 1) sum += __shfl_xor(sum, off, 64);
      float rs = 1.f/sum;
      s[0][r] = e0*rs; s[1][r] = e1*rs; s[2][r] = e2*rs; s[3][r] = e3*rs;
    }
    // P -> per-wave LDS (stride 144B, 2-way max)
    #pragma unroll
    for (int nf = 0; nf < 4; ++nf){
      int j = nf*16 + l15;
      #pragma unroll
      for (int r = 0; r < 4; ++r)
        *(u16*)(pbw + (lg*4+r)*144 + j*2) = f2b(s[nf][r]);
    }
    // PV
    f32x4 o0 = (f32x4){0.f,0.f,0.f,0.f}, o1 = o0;
    #pragma unroll
    for (int ksp = 0; ksp < 2; ++ksp){
      bf16x8 pa = *(const bf16x8*)(pbw + l15*144 + ksp*64 + lg*16);
      o0 = __builtin_amdgcn_mfma_f32_16x16x32_bf16(pa, vb0[ksp], o0, 0, 0, 0);
      o1 = __builtin_amdgcn_mfma_f32_16x16x32_bf16(pa, vb1[ksp], o1, 0, 0, 0);
    }
    #pragma unroll
    for (int r = 0; r < 4; ++r){
      int row = wid*16 + lg*4 + r;
      if (row < 49){
        u16* dst = outwin + ((size_t)win*49 + row)*DIM + h*HD;
        dst[l15]      = f2b(o0[r]);
        dst[16 + l15] = f2b(o1[r]);
      }
    }
  }
}

// ---------------- proj + window-reverse + LN1 + residual -> x1 (d_out), MFMA ----------------
__global__ __launch_bounds__(256) void k_proj(
    const u16* __restrict__ outwin, const u16* __restrict__ pwbf,
    const float* __restrict__ proj_b, const float* __restrict__ x,
    const float* __restrict__ n1g, const float* __restrict__ n1b,
    float* __restrict__ x1){
  __shared__ __align__(16) char sb[49152];     // 64x384 bf16 swizzled
  int tid  = threadIdx.x;
  int lane = tid & 63, wid = tid >> 6;
  int l15  = lane & 15, lg = lane >> 4;
  int gt0 = blockIdx.x * 64;

  for (int e = tid; e < 64*48; e += 256){      // gather (window-reverse) 64 token rows
    int r = e / 48, q8 = e - (e/48)*48;
    int gtok = gt0 + r;
    int b = gtok / 3136, r2 = gtok - b*3136;
    int oh = r2 / 56, ow = r2 - oh*56;
    int hs = oh + 53; if (hs >= 56) hs -= 56;
    int ws2 = ow + 53; if (ws2 >= 56) ws2 -= 56;
    int win = b*64 + (hs/7)*8 + (ws2/7);
    int row = (hs%7)*7 + (ws2%7);
    bf16x8 v = *(const bf16x8*)(outwin + ((size_t)win*49 + row)*DIM + q8*8);
    *(bf16x8*)(sb + r*768 + ((q8*16) ^ ((r&7)<<4))) = v;
  }
  f32x4 acc[24];
  #pragma unroll
  for (int nf = 0; nf < 24; ++nf){
    float pbv = proj_b[nf*16 + l15];
    acc[nf] = (f32x4){pbv, pbv, pbv, pbv};
  }
  __syncthreads();
  #pragma unroll 2
  for (int ksp = 0; ksp < 12; ++ksp){
    int k0 = ksp*32 + lg*8;
    int arow = wid*16 + l15;
    bf16x8 af = *(const bf16x8*)(sb + arow*768 + ((k0*2) ^ ((arow&7)<<4)));
    #pragma unroll
    for (int nf = 0; nf < 24; ++nf){
      bf16x8 bfv = *(const bf16x8*)(pwbf + (size_t)(nf*16+l15)*DIM + k0);
      acc[nf] = __builtin_amdgcn_mfma_f32_16x16x32_bf16(af, bfv, acc[nf], 0, 0, 0);
    }
  }
  float s1[4] = {0.f,0.f,0.f,0.f}, s2[4] = {0.f,0.f,0.f,0.f};
  #pragma unroll
  for (int nf = 0; nf < 24; ++nf)
    #pragma unroll
    for (int r = 0; r < 4; ++r){
      float v = acc[nf][r];
      s1[r] += v; s2[r] += v*v;
    }
  #pragma unroll
  for (int r = 0; r < 4; ++r){
    #pragma unroll
    for (int off = 1; off < 16; off <<= 1){
      s1[r] += __shfl_xor(s1[r], off, 64);
      s2[r] += __shfl_xor(s2[r], off, 64);
    }
  }
  #pragma unroll
  for (int r = 0; r < 4; ++r){
    float mu = s1[r]*(1.f/384.f);
    float rstd = rsqrtf(s2[r]*(1.f/384.f) - mu*mu + 1e-5f);
    int grow = gt0 + wid*16 + lg*4 + r;
    #pragma unroll
    for (int nf = 0; nf < 24; ++nf){
      int col = nf*16 + l15;
      x1[(size_t)grow*DIM + col] =
          (acc[nf][r]-mu)*rstd*n1g[col] + n1b[col] + x[(size_t)grow*DIM + col];
    }
  }
}

// ---------------- fused MLP v3: 512 thr / 8 waves, 64 tokens/block ----------------
__global__ __launch_bounds__(512, 4) void k_mlp(
    const float* __restrict__ x1, const u16* __restrict__ w1bf, const float* __restrict__ b1,
    const u16* __restrict__ w2bf, const float* __restrict__ b2,
    const float* __restrict__ n2g, const float* __restrict__ n2b,
    float* __restrict__ out){
  __shared__ __align__(16) char smem[65536];
  char* xb = smem;                 // [64][768B] bf16, swz ^((row&15)<<4)
  char* hb = smem + 49152;         // [64][256B] bf16, swz ^((row&15)<<4)

  int tid  = threadIdx.x;
  int lane = tid & 63, wid = tid >> 6;
  int l15  = lane & 15, lg = lane >> 4;
  int wm = wid >> 2, wn = wid & 3;
  int gt0 = blockIdx.x * 64;

  for (int e = tid; e < 64*48; e += 512){
    int r = e / 48, q8 = e - (e/48)*48;
    const float4* src = (const float4*)(x1 + (size_t)(gt0+r)*DIM + q8*8);
    float4 a = src[0], c = src[1];
    bf16x8 v;
    v[0]=(short)f2b(a.x); v[1]=(short)f2b(a.y); v[2]=(short)f2b(a.z); v[3]=(short)f2b(a.w);
    v[4]=(short)f2b(c.x); v[5]=(short)f2b(c.y); v[6]=(short)f2b(c.z); v[7]=(short)f2b(c.w);
    *(bf16x8*)(xb + r*768 + ((q8*16) ^ ((r&15)<<4))) = v;
  }

  f32x4 acc2[4][3];
  #pragma unroll
  for (int mf = 0; mf < 4; ++mf)
    #pragma unroll
    for (int t = 0; t < 3; ++t){
      float bb = b2[(wid + 8*t)*16 + l15];
      acc2[mf][t] = (f32x4){bb, bb, bb, bb};
    }
  __syncthreads();

  for (int hc = 0; hc < 1536; hc += 128){
    f32x4 accH[2][2];
    #pragma unroll
    for (int mf = 0; mf < 2; ++mf)
      #pragma unroll
      for (int nh = 0; nh < 2; ++nh){
        float bb = b1[hc + wn*32 + nh*16 + l15];
        accH[mf][nh] = (f32x4){bb, bb, bb, bb};
      }
    #pragma unroll 2
    for (int ksp = 0; ksp < 12; ++ksp){
      int k0 = ksp*32 + lg*8;
      bf16x8 afr[2], bfr[2];
      #pragma unroll
      for (int mf = 0; mf < 2; ++mf){
        int row = wm*32 + mf*16 + l15;
        afr[mf] = *(const bf16x8*)(xb + row*768 + ((k0*2) ^ ((row&15)<<4)));
      }
      #pragma unroll
      for (int nh = 0; nh < 2; ++nh)
        bfr[nh] = *(const bf16x8*)(w1bf + (size_t)(hc + wn*32 + nh*16 + l15)*384 + k0);
      #pragma unroll
      for (int mf = 0; mf < 2; ++mf)
        #pragma unroll
        for (int nh = 0; nh < 2; ++nh)
          accH[mf][nh] = __builtin_amdgcn_mfma_f32_16x16x32_bf16(afr[mf], bfr[nh], accH[mf][nh], 0, 0, 0);
    }
    #pragma unroll
    for (int mf = 0; mf < 2; ++mf)
      #pragma unroll
      for (int nh = 0; nh < 2; ++nh)
        #pragma unroll
        for (int r = 0; r < 4; ++r){
          float v = accH[mf][nh][r];
          v = 0.5f*v*(1.f + erff(v*0.70710678f));
          int row = wm*32 + mf*16 + lg*4 + r;
          int col = wn*32 + nh*16 + l15;
          *(u16*)(hb + row*256 + ((col*2) ^ ((row&15)<<4))) = f2b(v);
        }
    __syncthreads();
    #pragma unroll
    for (int ks = 0; ks < 4; ++ks){
      int k0 = ks*32 + lg*8;
      bf16x8 pa[4];
      #pragma unroll
      for (int mf = 0; mf < 4; ++mf){
        int row = mf*16 + l15;
        pa[mf] = *(const bf16x8*)(hb + row*256 + ((k0*2) ^ ((row&15)<<4)));
      }
      #pragma unroll
      for (int t = 0; t < 3; ++t){
        bf16x8 pbt = *(const bf16x8*)(w2bf + (size_t)((wid + 8*t)*16 + l15)*1536 + hc + k0);
        #pragma unroll
        for (int mf = 0; mf < 4; ++mf)
          acc2[mf][t] = __builtin_amdgcn_mfma_f32_16x16x32_bf16(pa[mf], pbt, acc2[mf][t], 0, 0, 0);
      }
    }
    __syncthreads();
  }

  float* part = (float*)hb;
  float* lnf  = (float*)(hb + 4096);
  float s1a[4][4], s2a[4][4];
  #pragma unroll
  for (int mf = 0; mf < 4; ++mf)
    #pragma unroll
    for (int r = 0; r < 4; ++r){
      float p1 = acc2[mf][0][r] + acc2[mf][1][r] + acc2[mf][2][r];
      float p2 = acc2[mf][0][r]*acc2[mf][0][r] + acc2[mf][1][r]*acc2[mf][1][r]
               + acc2[mf][2][r]*acc2[mf][2][r];
      #pragma unroll
      for (int off = 1; off < 16; off <<= 1){
        p1 += __shfl_xor(p1, off, 64);
        p2 += __shfl_xor(p2, off, 64);
      }
      s1a[mf][r] = p1; s2a[mf][r] = p2;
    }
  if (l15 == 0){
    #pragma unroll
    for (int mf = 0; mf < 4; ++mf)
      #pragma unroll
      for (int r = 0; r < 4; ++r){
        int row = mf*16 + lg*4 + r;
        part[(row*8 + wid)*2]     = s1a[mf][r];
        part[(row*8 + wid)*2 + 1] = s2a[mf][r];
      }
  }
  __syncthreads();
  if (tid < 64){
    float t1 = 0.f, t2 = 0.f;
    #pragma unroll
    for (int w = 0; w < 8; ++w){
      t1 += part[(tid*8 + w)*2];
      t2 += part[(tid*8 + w)*2 + 1];
    }
    float mu = t1*(1.f/384.f);
    lnf[tid*2]     = mu;
    lnf[tid*2 + 1] = rsqrtf(t2*(1.f/384.f) - mu*mu + 1e-5f);
  }
  __syncthreads();
  #pragma unroll
  for (int mf = 0; mf < 4; ++mf)
    #pragma unroll
    for (int r = 0; r < 4; ++r){
      int row = mf*16 + lg*4 + r;
      float mu = lnf[row*2], rstd = lnf[row*2 + 1];
      #pragma unroll
      for (int t = 0; t < 3; ++t){
        int col = (wid + 8*t)*16 + l15;
        float resid = b2f(*(const u16*)(xb + row*768 + ((col*2) ^ ((row&15)<<4))));
        out[(size_t)(gt0 + row)*DIM + col] =
            resid + (acc2[mf][t][r]-mu)*rstd*n2g[col] + n2b[col];
      }
    }
}

extern "C" void kernel_launch(void* const* d_in, const int* in_sizes, int n_in,
                              void* d_out, int out_size, void* d_ws, size_t ws_size,
                              hipStream_t stream){
  const float* x           = (const float*)d_in[0];
  const float* qkv_w       = (const float*)d_in[1];
  const float* q_bias      = (const float*)d_in[2];
  const float* v_bias      = (const float*)d_in[3];
  const float* logit_scale = (const float*)d_in[4];
  const float* cpb_w1      = (const float*)d_in[5];
  const float* cpb_b1      = (const float*)d_in[6];
  const float* cpb_w2      = (const float*)d_in[7];
  const float* proj_w      = (const float*)d_in[8];
  const float* proj_b      = (const float*)d_in[9];
  const float* n1g         = (const float*)d_in[10];
  const float* n1b         = (const float*)d_in[11];
  const float* n2g         = (const float*)d_in[12];
  const float* n2b         = (const float*)d_in[13];
  const float* mlp_w1      = (const float*)d_in[14];
  const float* mlp_b1      = (const float*)d_in[15];
  const float* mlp_w2      = (const float*)d_in[16];
  const float* mlp_b2      = (const float*)d_in[17];

  // ws (80.7 MB, unchanged): tab 8K | biasfull 116K | Q/outwin 77.07M | qkvbf | pwbf | w1bf | w2bf
  // d_out scratch before k_proj: K (77.07M) | V (77.07M) = exactly out_size*4.
  char* ws = (char*)d_ws;
  float* tab      = (float*)ws;
  float* biasfull = (float*)(ws + 8192);
  u16*  Qg     = (u16*)(ws + 126976);                  // aliased by outwin after k_attn2
  u16*  qkvbf  = (u16*)(ws + 126976 + 77070336ull);
  u16*  pwbf   = (u16*)(ws + 126976 + 77070336ull + 884736ull);
  u16*  w1bf   = (u16*)(ws + 126976 + 77070336ull + 884736ull + 294912ull);
  u16*  w2bf   = (u16*)(ws + 126976 + 77070336ull + 884736ull + 294912ull + 1179648ull);
  u16*  Kg     = (u16*)d_out;
  u16*  Vg     = Kg + (size_t)NWIN*18816;
  u16*  outwin = Qg;
  float* x1  = (float*)d_out;
  float* out = (float*)d_out;

  hipLaunchKernelGGL(k_bias, dim3(169), dim3(256), 0, stream, cpb_w1, cpb_b1, cpb_w2, tab);
  hipLaunchKernelGGL(k_bias2, dim3(12), dim3(256), 0, stream, tab, biasfull);
  hipLaunchKernelGGL(k_wconv, dim3(1024), dim3(256), 0, stream,
                     mlp_w1, mlp_w2, qkv_w, proj_w, w1bf, w2bf, qkvbf, pwbf);
  hipLaunchKernelGGL(k_qkv, dim3(NWIN, 3), dim3(512), 0, stream,
                     x, qkvbf, q_bias, v_bias, logit_scale, Qg, Kg, Vg);
  hipLaunchKernelGGL(k_attn2, dim3(NWIN), dim3(256), 0, stream,
                     Qg, Kg, Vg, biasfull, outwin);
  hipLaunchKernelGGL(k_proj, dim3(TOKENS/64), dim3(256), 0, stream,
                     outwin, pwbf, proj_b, x, n1g, n1b, x1);
  hipLaunchKernelGGL(k_mlp, dim3(TOKENS/64), dim3(512), 0, stream,
                     x1, w1bf, mlp_b1, w2bf, mlp_b2, n2g, n2b, out);
}